// Round 14
// baseline (145.877 us; speedup 1.0000x reference)
//
#include <hip/hip_runtime.h>
#include <hip/hip_bf16.h>

#define SS 2048      // sequence per batch after reshape
#define DK 64        // head dim
#define NB 16        // batches after reshape

typedef unsigned short u16;
typedef u16   u16x8 __attribute__((ext_vector_type(8)));
typedef u16   u16x4 __attribute__((ext_vector_type(4)));
typedef short s16x8 __attribute__((ext_vector_type(8)));
typedef float f32x16 __attribute__((ext_vector_type(16)));
typedef unsigned u32x4 __attribute__((ext_vector_type(4)));

__device__ __forceinline__ u16 f2bf(float f) {
    unsigned u = __builtin_bit_cast(unsigned, f);
    return (u16)((u + 0x7fffu + ((u >> 16) & 1u)) >> 16);   // RNE
}
__device__ __forceinline__ float bf2f(u16 v) {
    unsigned u = ((unsigned)v) << 16;
    return __builtin_bit_cast(float, u);
}
__device__ __forceinline__ unsigned cvtpk(float lo, float hi) {
    unsigned d;
    asm("v_cvt_pk_bf16_f32 %0, %1, %2" : "=v"(d) : "v"(lo), "v"(hi));
    return d;
}
__device__ __forceinline__ f32x16 zero16() {
    f32x16 z;
    #pragma unroll
    for (int i = 0; i < 16; ++i) z[i] = 0.f;
    return z;
}

// ============================================================================
// Prep: K -> bf16 Kb[b][t][d]; V -> bf16 VTb[b][d][t]; R -> bf16 RTb[c][d]
// One kernel, block-ranges: [0,2048)=K, [2048,2560)=V^T, [2560,2592)=R^T
// ============================================================================
__launch_bounds__(256)
__global__ void prep_kernel(const float* __restrict__ K,
                            const float* __restrict__ V,
                            const float* __restrict__ R,
                            u16* __restrict__ Kb,
                            u16* __restrict__ VTb,
                            u16* __restrict__ RTb) {
    __shared__ float tl[64][65];
    const int bid = blockIdx.x, tid = threadIdx.x;

    if (bid < 2048) {                       // --- K elementwise convert ---
        size_t i0 = ((size_t)bid * 256 + tid) * 4;
        float4 v = *(const float4*)(K + i0);
        u16x4 o;
        o[0] = f2bf(v.x); o[1] = f2bf(v.y); o[2] = f2bf(v.z); o[3] = f2bf(v.w);
        *(u16x4*)(Kb + i0) = o;
    } else if (bid < 2560) {                // --- V transpose (per batch) ---
        int u = bid - 2048;
        int bb = u >> 5, t0 = (u & 31) * 64;
        #pragma unroll
        for (int p = 0; p < 4; ++p) {
            int tt = (tid >> 4) + p * 16;
            int d0 = (tid & 15) * 4;
            float4 v = *(const float4*)(V + ((size_t)(bb * SS + t0 + tt)) * DK + d0);
            tl[tt][d0 + 0] = v.x; tl[tt][d0 + 1] = v.y;
            tl[tt][d0 + 2] = v.z; tl[tt][d0 + 3] = v.w;
        }
        __syncthreads();
        int d = tid >> 2, q = tid & 3;
        #pragma unroll
        for (int v2 = 0; v2 < 8; ++v2) {
            int t = q * 16 + 2 * v2;
            unsigned dw = ((unsigned)f2bf(tl[t + 1][d]) << 16) | f2bf(tl[t][d]);
            *(unsigned*)(VTb + ((size_t)(bb * DK + d)) * SS + t0 + t) = dw;
        }
    } else {                                // --- R transpose ---
        int u = bid - 2560;
        int c0 = u * 64;
        #pragma unroll
        for (int p = 0; p < 4; ++p) {
            int dd = (tid >> 4) + p * 16;
            int cc0 = (tid & 15) * 4;
            float4 v = *(const float4*)(R + (size_t)dd * SS + c0 + cc0);
            tl[dd][cc0 + 0] = v.x; tl[dd][cc0 + 1] = v.y;
            tl[dd][cc0 + 2] = v.z; tl[dd][cc0 + 3] = v.w;
        }
        __syncthreads();
        int cc = tid >> 2, q = tid & 3;
        #pragma unroll
        for (int v2 = 0; v2 < 8; ++v2) {
            int d = q * 16 + 2 * v2;
            unsigned dw = ((unsigned)f2bf(tl[d + 1][cc]) << 16) | f2bf(tl[d][cc]);
            *(unsigned*)(RTb + ((size_t)(c0 + cc)) * DK + d) = dw;
        }
    }
}

// ============================================================================
// MFMA flash attention with skewed relative-position bias — KEY-PARITY SPLIT.
// BISECT ROUND: r11 green kernel (93us kernel, absmax 0.0156) with EXACTLY ONE
// change: V^T is read direct from global/L2 instead of via the VTl staging
// (addresses derived from the staged algebra and verified element-identical:
// element = VTb[(b*64+d)*SS + t0 + 16c + 8h], d = sl / 32+sl — the XOR swizzle
// cancels between write and read). The 8-chunk staging loop is deleted; BOTH
// in-loop barriers, the lockstep active-guard loop, the jj map, the engine,
// and the scr-alias merge are byte-identical to r11. If this is green, r13's
// NaN is pinned on the barrier removal; if NaN, direct-V is convicted.
// ============================================================================
__launch_bounds__(256, 1)
__global__ void attn_mfma(const float* __restrict__ Q,
                          const u16* __restrict__ Kb,
                          const u16* __restrict__ VTb,
                          const u16* __restrict__ RTb,
                          float* __restrict__ O) {
    // LDS: 2*16K (merge scratch region, was V^T tiles) + 16K (QP rings) = 48 KiB
    __shared__ alignas(16) u16 VTl[2][64 * 128];    // merge scratch only now
    __shared__ alignas(16) u16 QPl[4][32 * 64];     // per wave ring [q=32][crel&63]

    const int tid  = threadIdx.x;
    const int b    = blockIdx.y;
    const int x    = blockIdx.x;                     // 0..31
    const int jjb  = ((x >> 1) + (b & 7) * 2) & 15;  // per-batch rotation (L2 spread)
    const int flip = (x & 1) ^ ((b >> 3) & 1);
    const int jj   = flip ? (31 - jjb) : jjb;        // 0..31, bijective per batch
    const int S0   = jj * 64;                        // q-tile first row
    const int wave = tid >> 6, lane = tid & 63;
    const int h    = lane >> 5, sl = lane & 31;
    const int grp  = wave >> 1, wv = wave & 1;
    const int s0w  = S0 + wv * 32;                   // wave's first q-row
    const int rtb  = wv ? 0 : 32;                    // wave offset in R window
    const int nTt  = (jj >> 1) + 1;                  // total 128-key tiles
    const int itMax = (nTt + 1) >> 1;                // group-0 count (>= group 1)
    unsigned* QPwU = (unsigned*)&QPl[wave][0];       // ALL QP access via unsigned

    // ---- Q B-fragments (scaled by 1/sqrt(dk)), shared by QK^T and QP ----
    s16x8 bq[4];
    {
        const float* Qr = Q + (size_t)(b * SS + s0w + sl) * DK;
        #pragma unroll
        for (int k = 0; k < 4; ++k) {
            float4 a = *(const float4*)(Qr + 16 * k + 8 * h);
            float4 c = *(const float4*)(Qr + 16 * k + 8 * h + 4);
            u16x8 t;
            t[0] = f2bf(a.x * 0.125f); t[1] = f2bf(a.y * 0.125f);
            t[2] = f2bf(a.z * 0.125f); t[3] = f2bf(a.w * 0.125f);
            t[4] = f2bf(c.x * 0.125f); t[5] = f2bf(c.y * 0.125f);
            t[6] = f2bf(c.z * 0.125f); t[7] = f2bf(c.w * 0.125f);
            bq[k] = __builtin_bit_cast(s16x8, t);
        }
    }

    f32x16 o0 = zero16(), o1 = zero16();
    float m = -3e38f, l = 0.f;

    // QP fragment: window GEMM piece -> rolling LDS ring. A-operand direct
    // from global RTb (element-identical to the old staged reads).
    auto qpfrag = [&](int mi, int cbase) {
        f32x16 acc = zero16();
        int c = cbase + rtb + mi * 32 + sl;
        c = max(0, min(2047, c));                    // clamped rows are masked later
        const u16* Rp = RTb + (size_t)c * DK + 8 * h;
        #pragma unroll
        for (int k = 0; k < 4; ++k) {
            s16x8 a = *(const s16x8*)(Rp + 16 * k);
            acc = __builtin_amdgcn_mfma_f32_32x32x16_bf16(a, bq[k], acc, 0, 0, 0);
        }
        #pragma unroll
        for (int R = 0; R < 4; ++R)
            #pragma unroll
            for (int rp = 0; rp < 2; ++rp) {
                int crel = mi * 32 + 8 * R + 2 * rp + 4 * h;
                unsigned dw = cvtpk(acc[4 * R + 2 * rp], acc[4 * R + 2 * rp + 1]);
                int col = (crel + 2 * sl) & 63;      // bank de-conflict swizzle
                QPwU[sl * 32 + (col >> 1)] = dw;
            }
    };
    auto biasmask = [&](f32x16& s, int ti, int t0, bool fullv) {
        #pragma unroll
        for (int r = 0; r < 16; ++r) {
            int off = (r & 3) + 8 * (r >> 2);
            int col = (31 + ti * 32 + off + 4 * h + sl) & 63;  // (crel + 2*sl)&63
            unsigned dv = QPwU[sl * 32 + (col >> 1)];
            float bias = bf2f((u16)(dv >> ((col & 1) * 16)));
            float v = s[r] + bias;
            if (!fullv) {
                int t = t0 + ti * 32 + off + 4 * h;
                v = (t <= s0w + sl) ? v : -3e38f;
            }
            s[r] = v;
        }
    };

    for (int it = 0; it < itMax; ++it) {
        const int tl = 2 * it + grp;                 // this group's tile
        const bool active = (tl < nTt);
        const int t0 = tl * 128;

        __syncthreads();                             // (kept: bisect purity)

        if (active) {
            const int cbase = 1984 + t0 - S0;        // R window base (>= 0)
            // ---- K A-fragments direct from global/L2 ----
            s16x8 kf[4][4];
            {
                const u16* Kp = Kb + (size_t)(b * SS + t0 + sl) * DK + 8 * h;
                #pragma unroll
                for (int ti = 0; ti < 4; ++ti)
                    #pragma unroll
                    for (int k = 0; k < 4; ++k)
                        kf[ti][k] = *(const s16x8*)(Kp + ti * 32 * DK + 16 * k);
            }
            auto qk = [&](int ti) -> f32x16 {
                f32x16 acc = zero16();
                #pragma unroll
                for (int k = 0; k < 4; ++k)
                    acc = __builtin_amdgcn_mfma_f32_32x32x16_bf16(kf[ti][k], bq[k], acc, 0, 0, 0);
                return acc;
            };

            const bool fullv = (t0 + 127 <= s0w);
            qpfrag(0, cbase); qpfrag(1, cbase);
            f32x16 s0v = qk(0); biasmask(s0v, 0, t0, fullv);
            qpfrag(2, cbase);
            f32x16 s1v = qk(1); biasmask(s1v, 1, t0, fullv);
            qpfrag(3, cbase);
            f32x16 s2v = qk(2); biasmask(s2v, 2, t0, fullv);
            qpfrag(4, cbase);
            f32x16 s3v = qk(3); biasmask(s3v, 3, t0, fullv);

            // ---- online softmax (column = q-row sl; in-lane + xor32) ----
            float tmax = -3e38f;
            #pragma unroll
            for (int r = 0; r < 16; ++r) {
                tmax = fmaxf(tmax, s0v[r]); tmax = fmaxf(tmax, s1v[r]);
                tmax = fmaxf(tmax, s2v[r]); tmax = fmaxf(tmax, s3v[r]);
            }
            tmax = fmaxf(tmax, __shfl_xor(tmax, 32));
            float mn = fmaxf(m, tmax);
            float corr = __expf(m - mn);
            m = mn;
            float ps = 0.f;
            #pragma unroll
            for (int r = 0; r < 16; ++r) {
                s0v[r] = __expf(s0v[r] - mn); ps += s0v[r];
                s1v[r] = __expf(s1v[r] - mn); ps += s1v[r];
                s2v[r] = __expf(s2v[r] - mn); ps += s2v[r];
                s3v[r] = __expf(s3v[r] - mn); ps += s3v[r];
            }
            l = l * corr + ps;
            #pragma unroll
            for (int r = 0; r < 16; ++r) { o0[r] *= corr; o1[r] *= corr; }

            // ---- pack P to bf16 dword pairs ----
            unsigned pd[4][4][2];
            #define PACK_P(TI, SV)                                            \
                _Pragma("unroll")                                             \
                for (int R = 0; R < 4; ++R) {                                 \
                    pd[TI][R][0] = cvtpk(SV[4 * R + 0], SV[4 * R + 1]);       \
                    pd[TI][R][1] = cvtpk(SV[4 * R + 2], SV[4 * R + 3]);       \
                }
            PACK_P(0, s0v) PACK_P(1, s1v) PACK_P(2, s2v) PACK_P(3, s3v)
            #undef PACK_P

            // ---- PV: O^T += VT . P^T ; B-frags via shfl_xor(32). V^T
            //      A-frags DIRECT from global (the ONE change vs r11):
            //      element = VTb[(b*64+d)*SS + t0 + 16c + 8h], d = sl / 32+sl.
            const u16* Vp0 = VTb + (size_t)(b * DK + sl) * SS + t0 + 8 * h;
            const u16* Vp1 = VTb + (size_t)(b * DK + 32 + sl) * SS + t0 + 8 * h;
            #pragma unroll
            for (int c = 0; c < 8; ++c) {
                const int ti = c >> 1;
                const int R0 = (2 * c) & 3, R1 = (2 * c + 1) & 3;
                unsigned a0 = pd[ti][R0][0], a1 = pd[ti][R0][1];
                unsigned b0 = pd[ti][R1][0], b1 = pd[ti][R1][1];
                unsigned xa0 = __shfl_xor(a0, 32), xa1 = __shfl_xor(a1, 32);
                unsigned xb0 = __shfl_xor(b0, 32), xb1 = __shfl_xor(b1, 32);
                u32x4 pw;
                pw[0] = h ? xb0 : a0;
                pw[1] = h ? xb1 : a1;
                pw[2] = h ? b0 : xa0;
                pw[3] = h ? b1 : xa1;
                s16x8 pb = __builtin_bit_cast(s16x8, pw);
                s16x8 va0 = *(const s16x8*)(Vp0 + 16 * c);
                s16x8 va1 = *(const s16x8*)(Vp1 + 16 * c);
                o0 = __builtin_amdgcn_mfma_f32_32x32x16_bf16(va0, pb, o0, 0, 0, 0);
                o1 = __builtin_amdgcn_mfma_f32_32x32x16_bf16(va1, pb, o1, 0, 0, 0);
            }
        }
        __syncthreads();
    }

    // ---- merge the two groups' partial flash states (same q-rows) ----
    float* scr = (float*)&VTl[0][0];                 // 2*64*34*4 = 17408B scratch
    if (grp == 1) {
        int base = (wv * 64 + lane) * 34;
        scr[base + 0] = m;
        scr[base + 1] = l;
        #pragma unroll
        for (int j = 0; j < 16; ++j) { scr[base + 2 + j] = o0[j]; scr[base + 18 + j] = o1[j]; }
    }
    __syncthreads();
    if (grp == 0) {
        int base = (wv * 64 + lane) * 34;
        float mB = scr[base + 0], lB = scr[base + 1];
        float M  = fmaxf(m, mB);
        float fa = __expf(m - M), fb = __expf(mB - M);   // inactive group: exp(-inf)=0
        float lt = l * fa + lB * fb;
        #pragma unroll
        for (int j = 0; j < 16; ++j) {
            o0[j] = o0[j] * fa + scr[base + 2 + j] * fb;
            o1[j] = o1[j] * fa + scr[base + 18 + j] * fb;
        }
        lt = lt + __shfl_xor(lt, 32);
        float inv = 1.0f / lt;
        float* Or = O + (size_t)(b * SS + s0w + sl) * DK;
        #pragma unroll
        for (int R = 0; R < 4; ++R) {
            float4 w;
            w.x = o0[4 * R + 0] * inv; w.y = o0[4 * R + 1] * inv;
            w.z = o0[4 * R + 2] * inv; w.w = o0[4 * R + 3] * inv;
            *(float4*)(Or + 8 * R + 4 * h) = w;
            w.x = o1[4 * R + 0] * inv; w.y = o1[4 * R + 1] * inv;
            w.z = o1[4 * R + 2] * inv; w.w = o1[4 * R + 3] * inv;
            *(float4*)(Or + 32 + 8 * R + 4 * h) = w;
        }
    }
}

// ============================================================================
// Fallback (round-1 fp32 kernel) — used only if ws_size is too small.
// ============================================================================
#define RT_ 64
#define TT_ 64
#define NWAVES_ 4
#define PATCH_C_ 128
#define PATCH_STRIDE_ 72

struct MrgT {
    float macc[RT_][DK + 1];
    float mw[NWAVES_][RT_];
    float lw[NWAVES_][RT_];
    float linv[RT_];
};
union SMemT {
    u16 patch[NWAVES_][PATCH_C_ * PATCH_STRIDE_];
    MrgT mrg;
};

__launch_bounds__(256)
__global__ void attn_relpos_fallback(const float* __restrict__ Q,
                                     const float* __restrict__ K,
                                     const float* __restrict__ V,
                                     const float* __restrict__ R,
                                     float* __restrict__ O) {
    __shared__ __attribute__((aligned(16))) SMemT sm;
    const int tileIdx = blockIdx.x;
    const int b       = blockIdx.y;
    const int r0      = tileIdx * RT_;
    const int wave    = __builtin_amdgcn_readfirstlane((int)(threadIdx.x >> 6));
    const int lane    = (int)(threadIdx.x & 63);
    const int s       = r0 + lane;

    float q[DK];
    {
        const float4* Qp = reinterpret_cast<const float4*>(Q + (size_t)(b * SS + s) * DK);
        #pragma unroll
        for (int i = 0; i < DK / 4; ++i) {
            float4 v = Qp[i];
            q[4*i+0] = v.x; q[4*i+1] = v.y; q[4*i+2] = v.z; q[4*i+3] = v.w;
        }
    }
    float acc[DK];
    #pragma unroll
    for (int d = 0; d < DK; ++d) acc[d] = 0.f;
    float m = -1e30f, l = 0.f;
    const int numT = r0 / TT_ + 1;

    for (int ti = wave; ti < numT; ti += NWAVES_) {
        const int t0 = ti * TT_;
        const int c0 = (SS - RT_) + t0 - r0;
        #pragma unroll
        for (int i = 0; i < 32; ++i) {
            const int d  = (lane >> 5) + 2 * i;
            const int cb = (lane & 31) * 4;
            const int c  = c0 + cb;
            float4 v = make_float4(0.f, 0.f, 0.f, 0.f);
            if (c < SS) v = *reinterpret_cast<const float4*>(R + (size_t)d * SS + c);
            u16* pw = &sm.patch[wave][0];
            pw[(cb + 0) * PATCH_STRIDE_ + d] = f2bf(v.x);
            pw[(cb + 1) * PATCH_STRIDE_ + d] = f2bf(v.y);
            pw[(cb + 2) * PATCH_STRIDE_ + d] = f2bf(v.z);
            pw[(cb + 3) * PATCH_STRIDE_ + d] = f2bf(v.w);
        }
        asm volatile("s_waitcnt lgkmcnt(0)" ::: "memory");
        const int ttlim = min(TT_ - 1, (r0 - t0) + lane);
        for (int tc = 0; tc < TT_; tc += 16) {
            float sc[16];
            #pragma unroll
            for (int j = 0; j < 16; ++j) {
                const int tt = tc + j;
                const int t  = t0 + tt;
                const float4* Kt4 = reinterpret_cast<const float4*>(K + (size_t)(b * SS + t) * DK);
                float a0 = 0.f, a1 = 0.f, a2 = 0.f, a3 = 0.f;
                #pragma unroll
                for (int i = 0; i < 16; ++i) {
                    float4 kv = Kt4[i];
                    a0 = fmaf(q[4*i+0], kv.x, a0);
                    a1 = fmaf(q[4*i+1], kv.y, a1);
                    a2 = fmaf(q[4*i+2], kv.z, a2);
                    a3 = fmaf(q[4*i+3], kv.w, a3);
                }
                const int cc = (RT_ - 1) + tt - lane;
                const u16* rp = &sm.patch[wave][cc * PATCH_STRIDE_];
                #pragma unroll
                for (int i = 0; i < 8; ++i) {
                    u16x8 v8 = *reinterpret_cast<const u16x8*>(rp + 8 * i);
                    a0 = fmaf(q[8*i+0], bf2f(v8[0]), a0);
                    a1 = fmaf(q[8*i+1], bf2f(v8[1]), a1);
                    a2 = fmaf(q[8*i+2], bf2f(v8[2]), a2);
                    a3 = fmaf(q[8*i+3], bf2f(v8[3]), a3);
                    a0 = fmaf(q[8*i+4], bf2f(v8[4]), a0);
                    a1 = fmaf(q[8*i+5], bf2f(v8[5]), a1);
                    a2 = fmaf(q[8*i+6], bf2f(v8[6]), a2);
                    a3 = fmaf(q[8*i+7], bf2f(v8[7]), a3);
                }
                const float v = ((a0 + a1) + (a2 + a3)) * 0.125f;
                sc[j] = (tt <= ttlim) ? v : -1e30f;
            }
            float cm = sc[0];
            #pragma unroll
            for (int j = 1; j < 16; ++j) cm = fmaxf(cm, sc[j]);
            const float nm   = fmaxf(m, cm);
            const float corr = __expf(m - nm);
            m = nm; l *= corr;
            #pragma unroll
            for (int d = 0; d < DK; ++d) acc[d] *= corr;
            #pragma unroll
            for (int j = 0; j < 16; ++j) {
                const int t = t0 + tc + j;
                const float p = __expf(sc[j] - m);
                l += p;
                const float4* Vt4 = reinterpret_cast<const float4*>(V + (size_t)(b * SS + t) * DK);
                #pragma unroll
                for (int i = 0; i < 16; ++i) {
                    float4 vv = Vt4[i];
                    acc[4*i+0] = fmaf(p, vv.x, acc[4*i+0]);
                    acc[4*i+1] = fmaf(p, vv.y, acc[4*i+1]);
                    acc[4*i+2] = fmaf(p, vv.z, acc[4*i+2]);
                    acc[4*i+3] = fmaf(p, vv.w, acc[4*i+3]);
                }
            }
        }
    }
    __syncthreads();
    sm.mrg.mw[wave][lane] = m;
    sm.mrg.lw[wave][lane] = l;
    __syncthreads();
    float M = sm.mrg.mw[0][lane];
    #pragma unroll
    for (int w = 1; w < NWAVES_; ++w) M = fmaxf(M, sm.mrg.mw[w][lane]);
    float L = 0.f;
    #pragma unroll
    for (int w = 0; w < NWAVES_; ++w) L += sm.mrg.lw[w][lane] * __expf(sm.mrg.mw[w][lane] - M);
    const float myscale = __expf(m - M);
    for (int w = 0; w < NWAVES_; ++w) {
        if (wave == w) {
            if (w == 0) {
                #pragma unroll
                for (int d = 0; d < DK; ++d) sm.mrg.macc[lane][d] = acc[d] * myscale;
            } else {
                #pragma unroll
                for (int d = 0; d < DK; ++d) sm.mrg.macc[lane][d] += acc[d] * myscale;
            }
        }
        __syncthreads();
    }
    if (wave == 0) sm.mrg.linv[lane] = 1.0f / L;
    __syncthreads();
    const int row = (int)(threadIdx.x >> 2);
    const int dq  = (int)(threadIdx.x & 3) * 16;
    const float li = sm.mrg.linv[row];
    float4* Orow = reinterpret_cast<float4*>(O + (size_t)(b * SS + r0 + row) * DK + dq);
    #pragma unroll
    for (int k2 = 0; k2 < 4; ++k2) {
        float4 o;
        o.x = sm.mrg.macc[row][dq + 4*k2 + 0] * li;
        o.y = sm.mrg.macc[row][dq + 4*k2 + 1] * li;
        o.z = sm.mrg.macc[row][dq + 4*k2 + 2] * li;
        o.w = sm.mrg.macc[row][dq + 4*k2 + 3] * li;
        Orow[k2] = o;
    }
}

extern "C" void kernel_launch(void* const* d_in, const int* in_sizes, int n_in,
                              void* d_out, int out_size, void* d_ws, size_t ws_size,
                              hipStream_t stream) {
    (void)in_sizes; (void)n_in; (void)out_size;
    const float* Q = (const float*)d_in[0];
    const float* K = (const float*)d_in[1];
    const float* V = (const float*)d_in[2];
    const float* R = (const float*)d_in[3];
    float* O = (float*)d_out;

    const size_t KB_ELEMS = (size_t)NB * SS * DK;    // 2,097,152
    const size_t RT_ELEMS = (size_t)SS * DK;         //   131,072
    const size_t NEED = (2 * KB_ELEMS + RT_ELEMS) * sizeof(u16);   // 8,650,752 B

    if (ws_size >= NEED) {
        u16* Kb  = (u16*)d_ws;
        u16* VTb = Kb + KB_ELEMS;
        u16* RTb = VTb + KB_ELEMS;
        prep_kernel<<<2592, 256, 0, stream>>>(K, V, R, Kb, VTb, RTb);
        attn_mfma<<<dim3(32, 16), 256, 0, stream>>>(Q, Kb, VTb, RTb, O);
    } else {
        attn_relpos_fallback<<<dim3(SS / RT_, NB), 256, 0, stream>>>(Q, K, V, R, O);
    }
}

// Round 15
// 144.234 us; speedup vs baseline: 1.0114x; 1.0114x over previous
//
#include <hip/hip_runtime.h>
#include <hip/hip_bf16.h>

#define SS 2048      // sequence per batch after reshape
#define DK 64        // head dim
#define NB 16        // batches after reshape

typedef unsigned short u16;
typedef u16   u16x8 __attribute__((ext_vector_type(8)));
typedef u16   u16x4 __attribute__((ext_vector_type(4)));
typedef short s16x8 __attribute__((ext_vector_type(8)));
typedef float f32x16 __attribute__((ext_vector_type(16)));
typedef unsigned u32x4 __attribute__((ext_vector_type(4)));

__device__ __forceinline__ u16 f2bf(float f) {
    unsigned u = __builtin_bit_cast(unsigned, f);
    return (u16)((u + 0x7fffu + ((u >> 16) & 1u)) >> 16);   // RNE
}
__device__ __forceinline__ float bf2f(u16 v) {
    unsigned u = ((unsigned)v) << 16;
    return __builtin_bit_cast(float, u);
}
__device__ __forceinline__ unsigned cvtpk(float lo, float hi) {
    unsigned d;
    asm("v_cvt_pk_bf16_f32 %0, %1, %2" : "=v"(d) : "v"(lo), "v"(hi));
    return d;
}
__device__ __forceinline__ f32x16 zero16() {
    f32x16 z;
    #pragma unroll
    for (int i = 0; i < 16; ++i) z[i] = 0.f;
    return z;
}

// ============================================================================
// Prep: K -> bf16 Kb[b][t][d]; V -> bf16 VTb[b][d][t]; R -> bf16 RTb[c][d]
// One kernel, block-ranges: [0,2048)=K, [2048,2560)=V^T, [2560,2592)=R^T
// ============================================================================
__launch_bounds__(256)
__global__ void prep_kernel(const float* __restrict__ K,
                            const float* __restrict__ V,
                            const float* __restrict__ R,
                            u16* __restrict__ Kb,
                            u16* __restrict__ VTb,
                            u16* __restrict__ RTb) {
    __shared__ float tl[64][65];
    const int bid = blockIdx.x, tid = threadIdx.x;

    if (bid < 2048) {                       // --- K elementwise convert ---
        size_t i0 = ((size_t)bid * 256 + tid) * 4;
        float4 v = *(const float4*)(K + i0);
        u16x4 o;
        o[0] = f2bf(v.x); o[1] = f2bf(v.y); o[2] = f2bf(v.z); o[3] = f2bf(v.w);
        *(u16x4*)(Kb + i0) = o;
    } else if (bid < 2560) {                // --- V transpose (per batch) ---
        int u = bid - 2048;
        int bb = u >> 5, t0 = (u & 31) * 64;
        #pragma unroll
        for (int p = 0; p < 4; ++p) {
            int tt = (tid >> 4) + p * 16;
            int d0 = (tid & 15) * 4;
            float4 v = *(const float4*)(V + ((size_t)(bb * SS + t0 + tt)) * DK + d0);
            tl[tt][d0 + 0] = v.x; tl[tt][d0 + 1] = v.y;
            tl[tt][d0 + 2] = v.z; tl[tt][d0 + 3] = v.w;
        }
        __syncthreads();
        int d = tid >> 2, q = tid & 3;
        #pragma unroll
        for (int v2 = 0; v2 < 8; ++v2) {
            int t = q * 16 + 2 * v2;
            unsigned dw = ((unsigned)f2bf(tl[t + 1][d]) << 16) | f2bf(tl[t][d]);
            *(unsigned*)(VTb + ((size_t)(bb * DK + d)) * SS + t0 + t) = dw;
        }
    } else {                                // --- R transpose ---
        int u = bid - 2560;
        int c0 = u * 64;
        #pragma unroll
        for (int p = 0; p < 4; ++p) {
            int dd = (tid >> 4) + p * 16;
            int cc0 = (tid & 15) * 4;
            float4 v = *(const float4*)(R + (size_t)dd * SS + c0 + cc0);
            tl[dd][cc0 + 0] = v.x; tl[dd][cc0 + 1] = v.y;
            tl[dd][cc0 + 2] = v.z; tl[dd][cc0 + 3] = v.w;
        }
        __syncthreads();
        int cc = tid >> 2, q = tid & 3;
        #pragma unroll
        for (int v2 = 0; v2 < 8; ++v2) {
            int d = q * 16 + 2 * v2;
            unsigned dw = ((unsigned)f2bf(tl[d + 1][cc]) << 16) | f2bf(tl[d][cc]);
            *(unsigned*)(RTb + ((size_t)(c0 + cc)) * DK + d) = dw;
        }
    }
}

// ============================================================================
// MFMA flash attention with skewed relative-position bias — 4-WAY KEY-PHASE.
// Block = 256 threads = 4 waves, ALL owning one 32-row q-slice; wave p takes
// key-tiles tl = 4*it + p (r11's proven lockstep/active-guard loop + one
// barrier per iteration — barriers are mandatory per r13/r14 bisect).
// All operands direct from global/L2 (K: r8-green, R: r9-green, V: r14-green).
// Grid (64,16) = 1024 blocks = 4096 waves (2x r11's supply); LDS 33.8KB ->
// 4 blocks/CU by LDS, ~3 waves/SIMD by VGPR. Merge = r11's lane-wise flash
// combine applied as a 2-stage tree (1->0, 3->2, then 2->0); empty phases
// carry m=-3e38,l=0 -> fb=0 (finite sentinels, no inf-inf).
// Engine formulas verbatim with unified window base cb0 = 2016 + t0 - s0w
// (algebraically equal to r11's cbase+rtb; crel = 31+ti*32+off+4h-sl same).
// Slice->block map pairs weight-w with weight-(5-w) slices (r11 hedge).
// ============================================================================
__launch_bounds__(256, 1)
__global__ void attn_mfma(const float* __restrict__ Q,
                          const u16* __restrict__ Kb,
                          const u16* __restrict__ VTb,
                          const u16* __restrict__ RTb,
                          float* __restrict__ O) {
    // LDS: QP rings 16K + 2-slot merge scratch 17K = 33.8 KiB
    __shared__ alignas(16) u16 QPl[4][32 * 64];     // per wave ring [q=32][crel&63]
    __shared__ alignas(16) float MRG[2][64][34];    // merge slots [slot][lane][m,l,o0,o1]

    const int tid  = threadIdx.x;
    const int b    = blockIdx.y;
    const int x    = blockIdx.x;                     // 0..63
    const int sib  = ((x >> 1) + (b & 7) * 4) & 31;  // per-batch rotation (L2 spread)
    const int flip = (x & 1) ^ ((b >> 3) & 1);
    const int si   = flip ? (63 - sib) : sib;        // slice 0..63, bijective per batch
    const int s0w  = si * 32;                        // slice's first q-row (all 4 waves)
    const int wave = tid >> 6, lane = tid & 63;
    const int h    = lane >> 5, sl = lane & 31;
    const int nTt  = (si >> 2) + 1;                  // total 128-key tiles for slice
    const int itMax = (nTt + 3) >> 2;                // lockstep trip count (1..4)
    unsigned* QPwU = (unsigned*)&QPl[wave][0];       // ALL QP access via unsigned

    // ---- Q B-fragments (scaled by 1/sqrt(dk)), shared by QK^T and QP ----
    s16x8 bq[4];
    {
        const float* Qr = Q + (size_t)(b * SS + s0w + sl) * DK;
        #pragma unroll
        for (int k = 0; k < 4; ++k) {
            float4 a = *(const float4*)(Qr + 16 * k + 8 * h);
            float4 c = *(const float4*)(Qr + 16 * k + 8 * h + 4);
            u16x8 t;
            t[0] = f2bf(a.x * 0.125f); t[1] = f2bf(a.y * 0.125f);
            t[2] = f2bf(a.z * 0.125f); t[3] = f2bf(a.w * 0.125f);
            t[4] = f2bf(c.x * 0.125f); t[5] = f2bf(c.y * 0.125f);
            t[6] = f2bf(c.z * 0.125f); t[7] = f2bf(c.w * 0.125f);
            bq[k] = __builtin_bit_cast(s16x8, t);
        }
    }

    f32x16 o0 = zero16(), o1 = zero16();
    float m = -3e38f, l = 0.f;

    // QP fragment: window GEMM piece -> rolling per-wave LDS ring. A-operand
    // direct from global RTb. Unified base: c = cb0 + mi*32 + sl.
    auto qpfrag = [&](int mi, int cb0) {
        f32x16 acc = zero16();
        int c = cb0 + mi * 32 + sl;
        c = max(0, min(2047, c));                    // clamped rows are masked later
        const u16* Rp = RTb + (size_t)c * DK + 8 * h;
        #pragma unroll
        for (int k = 0; k < 4; ++k) {
            s16x8 a = *(const s16x8*)(Rp + 16 * k);
            acc = __builtin_amdgcn_mfma_f32_32x32x16_bf16(a, bq[k], acc, 0, 0, 0);
        }
        #pragma unroll
        for (int R = 0; R < 4; ++R)
            #pragma unroll
            for (int rp = 0; rp < 2; ++rp) {
                int crel = mi * 32 + 8 * R + 2 * rp + 4 * h;
                unsigned dw = cvtpk(acc[4 * R + 2 * rp], acc[4 * R + 2 * rp + 1]);
                int col = (crel + 2 * sl) & 63;      // bank de-conflict swizzle
                QPwU[sl * 32 + (col >> 1)] = dw;
            }
    };
    auto biasmask = [&](f32x16& s, int ti, int t0, bool fullv) {
        #pragma unroll
        for (int r = 0; r < 16; ++r) {
            int off = (r & 3) + 8 * (r >> 2);
            int col = (31 + ti * 32 + off + 4 * h + sl) & 63;  // (crel + 2*sl)&63
            unsigned dv = QPwU[sl * 32 + (col >> 1)];
            float bias = bf2f((u16)(dv >> ((col & 1) * 16)));
            float v = s[r] + bias;
            if (!fullv) {
                int t = t0 + ti * 32 + off + 4 * h;
                v = (t <= s0w + sl) ? v : -3e38f;
            }
            s[r] = v;
        }
    };

    for (int it = 0; it < itMax; ++it) {
        const int tl = 4 * it + wave;                // this wave's key-tile
        const bool active = (tl < nTt);
        const int t0 = tl * 128;

        if (active) {
            const int cb0 = 2016 + t0 - s0w;         // >= 0 (s0w <= 2016)
            // ---- K A-fragments direct from global/L2 (r8-green) ----
            s16x8 kf[4][4];
            {
                const u16* Kp = Kb + (size_t)(b * SS + t0 + sl) * DK + 8 * h;
                #pragma unroll
                for (int ti = 0; ti < 4; ++ti)
                    #pragma unroll
                    for (int k = 0; k < 4; ++k)
                        kf[ti][k] = *(const s16x8*)(Kp + ti * 32 * DK + 16 * k);
            }
            auto qk = [&](int ti) -> f32x16 {
                f32x16 acc = zero16();
                #pragma unroll
                for (int k = 0; k < 4; ++k)
                    acc = __builtin_amdgcn_mfma_f32_32x32x16_bf16(kf[ti][k], bq[k], acc, 0, 0, 0);
                return acc;
            };

            const bool fullv = (t0 + 127 <= s0w);
            qpfrag(0, cb0); qpfrag(1, cb0);
            f32x16 s0v = qk(0); biasmask(s0v, 0, t0, fullv);
            qpfrag(2, cb0);
            f32x16 s1v = qk(1); biasmask(s1v, 1, t0, fullv);
            qpfrag(3, cb0);
            f32x16 s2v = qk(2); biasmask(s2v, 2, t0, fullv);
            qpfrag(4, cb0);
            f32x16 s3v = qk(3); biasmask(s3v, 3, t0, fullv);

            // ---- online softmax (column = q-row sl; in-lane + xor32) ----
            float tmax = -3e38f;
            #pragma unroll
            for (int r = 0; r < 16; ++r) {
                tmax = fmaxf(tmax, s0v[r]); tmax = fmaxf(tmax, s1v[r]);
                tmax = fmaxf(tmax, s2v[r]); tmax = fmaxf(tmax, s3v[r]);
            }
            tmax = fmaxf(tmax, __shfl_xor(tmax, 32));
            float mn = fmaxf(m, tmax);
            float corr = __expf(m - mn);
            m = mn;
            float ps = 0.f;
            #pragma unroll
            for (int r = 0; r < 16; ++r) {
                s0v[r] = __expf(s0v[r] - mn); ps += s0v[r];
                s1v[r] = __expf(s1v[r] - mn); ps += s1v[r];
                s2v[r] = __expf(s2v[r] - mn); ps += s2v[r];
                s3v[r] = __expf(s3v[r] - mn); ps += s3v[r];
            }
            l = l * corr + ps;
            #pragma unroll
            for (int r = 0; r < 16; ++r) { o0[r] *= corr; o1[r] *= corr; }

            // ---- pack P to bf16 dword pairs ----
            unsigned pd[4][4][2];
            #define PACK_P(TI, SV)                                            \
                _Pragma("unroll")                                             \
                for (int R = 0; R < 4; ++R) {                                 \
                    pd[TI][R][0] = cvtpk(SV[4 * R + 0], SV[4 * R + 1]);       \
                    pd[TI][R][1] = cvtpk(SV[4 * R + 2], SV[4 * R + 3]);       \
                }
            PACK_P(0, s0v) PACK_P(1, s1v) PACK_P(2, s2v) PACK_P(3, s3v)
            #undef PACK_P

            // ---- PV: O^T += VT . P^T ; B-frags via shfl_xor(32). V^T
            //      A-frags direct from global (r14-green addressing):
            //      element = VTb[(b*64+d)*SS + t0 + 16c + 8h], d = sl / 32+sl.
            const u16* Vp0 = VTb + (size_t)(b * DK + sl) * SS + t0 + 8 * h;
            const u16* Vp1 = VTb + (size_t)(b * DK + 32 + sl) * SS + t0 + 8 * h;
            #pragma unroll
            for (int c = 0; c < 8; ++c) {
                const int ti = c >> 1;
                const int R0 = (2 * c) & 3, R1 = (2 * c + 1) & 3;
                unsigned a0 = pd[ti][R0][0], a1 = pd[ti][R0][1];
                unsigned b0 = pd[ti][R1][0], b1 = pd[ti][R1][1];
                unsigned xa0 = __shfl_xor(a0, 32), xa1 = __shfl_xor(a1, 32);
                unsigned xb0 = __shfl_xor(b0, 32), xb1 = __shfl_xor(b1, 32);
                u32x4 pw;
                pw[0] = h ? xb0 : a0;
                pw[1] = h ? xb1 : a1;
                pw[2] = h ? b0 : xa0;
                pw[3] = h ? b1 : xa1;
                s16x8 pb = __builtin_bit_cast(s16x8, pw);
                s16x8 va0 = *(const s16x8*)(Vp0 + 16 * c);
                s16x8 va1 = *(const s16x8*)(Vp1 + 16 * c);
                o0 = __builtin_amdgcn_mfma_f32_32x32x16_bf16(va0, pb, o0, 0, 0, 0);
                o1 = __builtin_amdgcn_mfma_f32_32x32x16_bf16(va1, pb, o1, 0, 0, 0);
            }
        }
        __syncthreads();   // per-iteration fence (mandatory per r13/r14 bisect)
    }

    // ---- 2-stage tree merge of the 4 phases' partial flash states ----
    auto mwrite = [&](int slot) {
        MRG[slot][lane][0] = m;
        MRG[slot][lane][1] = l;
        #pragma unroll
        for (int j = 0; j < 16; ++j) {
            MRG[slot][lane][2 + j]  = o0[j];
            MRG[slot][lane][18 + j] = o1[j];
        }
    };
    auto mcombine = [&](int slot) {
        float mB = MRG[slot][lane][0], lB = MRG[slot][lane][1];
        float M  = fmaxf(m, mB);
        float fa = __expf(m - M), fb = __expf(mB - M);   // empty side -> factor 0
        l = l * fa + lB * fb;
        #pragma unroll
        for (int j = 0; j < 16; ++j) {
            o0[j] = o0[j] * fa + MRG[slot][lane][2 + j]  * fb;
            o1[j] = o1[j] * fa + MRG[slot][lane][18 + j] * fb;
        }
        m = M;
    };

    if (wave == 1 || wave == 3) mwrite(wave >> 1);       // 1->slot0, 3->slot1
    __syncthreads();
    if (wave == 0 || wave == 2) mcombine(wave >> 1);     // 0<=slot0, 2<=slot1
    __syncthreads();
    if (wave == 2) mwrite(0);
    __syncthreads();
    if (wave == 0) {
        mcombine(0);
        float lt = l + __shfl_xor(l, 32);
        float inv = 1.0f / lt;
        float* Or = O + (size_t)(b * SS + s0w + sl) * DK;
        #pragma unroll
        for (int R = 0; R < 4; ++R) {
            float4 w;
            w.x = o0[4 * R + 0] * inv; w.y = o0[4 * R + 1] * inv;
            w.z = o0[4 * R + 2] * inv; w.w = o0[4 * R + 3] * inv;
            *(float4*)(Or + 8 * R + 4 * h) = w;
            w.x = o1[4 * R + 0] * inv; w.y = o1[4 * R + 1] * inv;
            w.z = o1[4 * R + 2] * inv; w.w = o1[4 * R + 3] * inv;
            *(float4*)(Or + 32 + 8 * R + 4 * h) = w;
        }
    }
}

// ============================================================================
// Fallback (round-1 fp32 kernel) — used only if ws_size is too small.
// ============================================================================
#define RT_ 64
#define TT_ 64
#define NWAVES_ 4
#define PATCH_C_ 128
#define PATCH_STRIDE_ 72

struct MrgT {
    float macc[RT_][DK + 1];
    float mw[NWAVES_][RT_];
    float lw[NWAVES_][RT_];
    float linv[RT_];
};
union SMemT {
    u16 patch[NWAVES_][PATCH_C_ * PATCH_STRIDE_];
    MrgT mrg;
};

__launch_bounds__(256)
__global__ void attn_relpos_fallback(const float* __restrict__ Q,
                                     const float* __restrict__ K,
                                     const float* __restrict__ V,
                                     const float* __restrict__ R,
                                     float* __restrict__ O) {
    __shared__ __attribute__((aligned(16))) SMemT sm;
    const int tileIdx = blockIdx.x;
    const int b       = blockIdx.y;
    const int r0      = tileIdx * RT_;
    const int wave    = __builtin_amdgcn_readfirstlane((int)(threadIdx.x >> 6));
    const int lane    = (int)(threadIdx.x & 63);
    const int s       = r0 + lane;

    float q[DK];
    {
        const float4* Qp = reinterpret_cast<const float4*>(Q + (size_t)(b * SS + s) * DK);
        #pragma unroll
        for (int i = 0; i < DK / 4; ++i) {
            float4 v = Qp[i];
            q[4*i+0] = v.x; q[4*i+1] = v.y; q[4*i+2] = v.z; q[4*i+3] = v.w;
        }
    }
    float acc[DK];
    #pragma unroll
    for (int d = 0; d < DK; ++d) acc[d] = 0.f;
    float m = -1e30f, l = 0.f;
    const int numT = r0 / TT_ + 1;

    for (int ti = wave; ti < numT; ti += NWAVES_) {
        const int t0 = ti * TT_;
        const int c0 = (SS - RT_) + t0 - r0;
        #pragma unroll
        for (int i = 0; i < 32; ++i) {
            const int d  = (lane >> 5) + 2 * i;
            const int cb = (lane & 31) * 4;
            const int c  = c0 + cb;
            float4 v = make_float4(0.f, 0.f, 0.f, 0.f);
            if (c < SS) v = *reinterpret_cast<const float4*>(R + (size_t)d * SS + c);
            u16* pw = &sm.patch[wave][0];
            pw[(cb + 0) * PATCH_STRIDE_ + d] = f2bf(v.x);
            pw[(cb + 1) * PATCH_STRIDE_ + d] = f2bf(v.y);
            pw[(cb + 2) * PATCH_STRIDE_ + d] = f2bf(v.z);
            pw[(cb + 3) * PATCH_STRIDE_ + d] = f2bf(v.w);
        }
        asm volatile("s_waitcnt lgkmcnt(0)" ::: "memory");
        const int ttlim = min(TT_ - 1, (r0 - t0) + lane);
        for (int tc = 0; tc < TT_; tc += 16) {
            float sc[16];
            #pragma unroll
            for (int j = 0; j < 16; ++j) {
                const int tt = tc + j;
                const int t  = t0 + tt;
                const float4* Kt4 = reinterpret_cast<const float4*>(K + (size_t)(b * SS + t) * DK);
                float a0 = 0.f, a1 = 0.f, a2 = 0.f, a3 = 0.f;
                #pragma unroll
                for (int i = 0; i < 16; ++i) {
                    float4 kv = Kt4[i];
                    a0 = fmaf(q[4*i+0], kv.x, a0);
                    a1 = fmaf(q[4*i+1], kv.y, a1);
                    a2 = fmaf(q[4*i+2], kv.z, a2);
                    a3 = fmaf(q[4*i+3], kv.w, a3);
                }
                const int cc = (RT_ - 1) + tt - lane;
                const u16* rp = &sm.patch[wave][cc * PATCH_STRIDE_];
                #pragma unroll
                for (int i = 0; i < 8; ++i) {
                    u16x8 v8 = *reinterpret_cast<const u16x8*>(rp + 8 * i);
                    a0 = fmaf(q[8*i+0], bf2f(v8[0]), a0);
                    a1 = fmaf(q[8*i+1], bf2f(v8[1]), a1);
                    a2 = fmaf(q[8*i+2], bf2f(v8[2]), a2);
                    a3 = fmaf(q[8*i+3], bf2f(v8[3]), a3);
                    a0 = fmaf(q[8*i+4], bf2f(v8[4]), a0);
                    a1 = fmaf(q[8*i+5], bf2f(v8[5]), a1);
                    a2 = fmaf(q[8*i+6], bf2f(v8[6]), a2);
                    a3 = fmaf(q[8*i+7], bf2f(v8[7]), a3);
                }
                const float v = ((a0 + a1) + (a2 + a3)) * 0.125f;
                sc[j] = (tt <= ttlim) ? v : -1e30f;
            }
            float cm = sc[0];
            #pragma unroll
            for (int j = 1; j < 16; ++j) cm = fmaxf(cm, sc[j]);
            const float nm   = fmaxf(m, cm);
            const float corr = __expf(m - nm);
            m = nm; l *= corr;
            #pragma unroll
            for (int d = 0; d < DK; ++d) acc[d] *= corr;
            #pragma unroll
            for (int j = 0; j < 16; ++j) {
                const int t = t0 + tc + j;
                const float p = __expf(sc[j] - m);
                l += p;
                const float4* Vt4 = reinterpret_cast<const float4*>(V + (size_t)(b * SS + t) * DK);
                #pragma unroll
                for (int i = 0; i < 16; ++i) {
                    float4 vv = Vt4[i];
                    acc[4*i+0] = fmaf(p, vv.x, acc[4*i+0]);
                    acc[4*i+1] = fmaf(p, vv.y, acc[4*i+1]);
                    acc[4*i+2] = fmaf(p, vv.z, acc[4*i+2]);
                    acc[4*i+3] = fmaf(p, vv.w, acc[4*i+3]);
                }
            }
        }
    }
    __syncthreads();
    sm.mrg.mw[wave][lane] = m;
    sm.mrg.lw[wave][lane] = l;
    __syncthreads();
    float M = sm.mrg.mw[0][lane];
    #pragma unroll
    for (int w = 1; w < NWAVES_; ++w) M = fmaxf(M, sm.mrg.mw[w][lane]);
    float L = 0.f;
    #pragma unroll
    for (int w = 0; w < NWAVES_; ++w) L += sm.mrg.lw[w][lane] * __expf(sm.mrg.mw[w][lane] - M);
    const float myscale = __expf(m - M);
    for (int w = 0; w < NWAVES_; ++w) {
        if (wave == w) {
            if (w == 0) {
                #pragma unroll
                for (int d = 0; d < DK; ++d) sm.mrg.macc[lane][d] = acc[d] * myscale;
            } else {
                #pragma unroll
                for (int d = 0; d < DK; ++d) sm.mrg.macc[lane][d] += acc[d] * myscale;
            }
        }
        __syncthreads();
    }
    if (wave == 0) sm.mrg.linv[lane] = 1.0f / L;
    __syncthreads();
    const int row = (int)(threadIdx.x >> 2);
    const int dq  = (int)(threadIdx.x & 3) * 16;
    const float li = sm.mrg.linv[row];
    float4* Orow = reinterpret_cast<float4*>(O + (size_t)(b * SS + r0 + row) * DK + dq);
    #pragma unroll
    for (int k2 = 0; k2 < 4; ++k2) {
        float4 o;
        o.x = sm.mrg.macc[row][dq + 4*k2 + 0] * li;
        o.y = sm.mrg.macc[row][dq + 4*k2 + 1] * li;
        o.z = sm.mrg.macc[row][dq + 4*k2 + 2] * li;
        o.w = sm.mrg.macc[row][dq + 4*k2 + 3] * li;
        Orow[k2] = o;
    }
}

extern "C" void kernel_launch(void* const* d_in, const int* in_sizes, int n_in,
                              void* d_out, int out_size, void* d_ws, size_t ws_size,
                              hipStream_t stream) {
    (void)in_sizes; (void)n_in; (void)out_size;
    const float* Q = (const float*)d_in[0];
    const float* K = (const float*)d_in[1];
    const float* V = (const float*)d_in[2];
    const float* R = (const float*)d_in[3];
    float* O = (float*)d_out;

    const size_t KB_ELEMS = (size_t)NB * SS * DK;    // 2,097,152
    const size_t RT_ELEMS = (size_t)SS * DK;         //   131,072
    const size_t NEED = (2 * KB_ELEMS + RT_ELEMS) * sizeof(u16);   // 8,650,752 B

    if (ws_size >= NEED) {
        u16* Kb  = (u16*)d_ws;
        u16* VTb = Kb + KB_ELEMS;
        u16* RTb = VTb + KB_ELEMS;
        prep_kernel<<<2592, 256, 0, stream>>>(K, V, R, Kb, VTb, RTb);
        attn_mfma<<<dim3(64, 16), 256, 0, stream>>>(Q, Kb, VTb, RTb, O);
    } else {
        attn_relpos_fallback<<<dim3(SS / RT_, NB), 256, 0, stream>>>(Q, K, V, R, O);
    }
}

// Round 16
// 121.163 us; speedup vs baseline: 1.2040x; 1.1904x over previous
//
#include <hip/hip_runtime.h>
#include <hip/hip_bf16.h>

#define SS 2048      // sequence per batch after reshape
#define DK 64        // head dim
#define NB 16        // batches after reshape

typedef unsigned short u16;
typedef u16   u16x8 __attribute__((ext_vector_type(8)));
typedef u16   u16x4 __attribute__((ext_vector_type(4)));
typedef short s16x8 __attribute__((ext_vector_type(8)));
typedef float f32x16 __attribute__((ext_vector_type(16)));
typedef unsigned u32x4 __attribute__((ext_vector_type(4)));

__device__ __forceinline__ u16 f2bf(float f) {
    unsigned u = __builtin_bit_cast(unsigned, f);
    return (u16)((u + 0x7fffu + ((u >> 16) & 1u)) >> 16);   // RNE
}
__device__ __forceinline__ float bf2f(u16 v) {
    unsigned u = ((unsigned)v) << 16;
    return __builtin_bit_cast(float, u);
}
__device__ __forceinline__ unsigned cvtpk(float lo, float hi) {
    unsigned d;
    asm("v_cvt_pk_bf16_f32 %0, %1, %2" : "=v"(d) : "v"(lo), "v"(hi));
    return d;
}
__device__ __forceinline__ f32x16 zero16() {
    f32x16 z;
    #pragma unroll
    for (int i = 0; i < 16; ++i) z[i] = 0.f;
    return z;
}

// ============================================================================
// Prep: K -> bf16 Kb[b][t][d]; V -> bf16 VTb[b][d][t]; R -> bf16 RTb[c][d]
// One kernel, block-ranges: [0,2048)=K, [2048,2560)=V^T, [2560,2592)=R^T
// ============================================================================
__launch_bounds__(256)
__global__ void prep_kernel(const float* __restrict__ K,
                            const float* __restrict__ V,
                            const float* __restrict__ R,
                            u16* __restrict__ Kb,
                            u16* __restrict__ VTb,
                            u16* __restrict__ RTb) {
    __shared__ float tl[64][65];
    const int bid = blockIdx.x, tid = threadIdx.x;

    if (bid < 2048) {                       // --- K elementwise convert ---
        size_t i0 = ((size_t)bid * 256 + tid) * 4;
        float4 v = *(const float4*)(K + i0);
        u16x4 o;
        o[0] = f2bf(v.x); o[1] = f2bf(v.y); o[2] = f2bf(v.z); o[3] = f2bf(v.w);
        *(u16x4*)(Kb + i0) = o;
    } else if (bid < 2560) {                // --- V transpose (per batch) ---
        int u = bid - 2048;
        int bb = u >> 5, t0 = (u & 31) * 64;
        #pragma unroll
        for (int p = 0; p < 4; ++p) {
            int tt = (tid >> 4) + p * 16;
            int d0 = (tid & 15) * 4;
            float4 v = *(const float4*)(V + ((size_t)(bb * SS + t0 + tt)) * DK + d0);
            tl[tt][d0 + 0] = v.x; tl[tt][d0 + 1] = v.y;
            tl[tt][d0 + 2] = v.z; tl[tt][d0 + 3] = v.w;
        }
        __syncthreads();
        int d = tid >> 2, q = tid & 3;
        #pragma unroll
        for (int v2 = 0; v2 < 8; ++v2) {
            int t = q * 16 + 2 * v2;
            unsigned dw = ((unsigned)f2bf(tl[t + 1][d]) << 16) | f2bf(tl[t][d]);
            *(unsigned*)(VTb + ((size_t)(bb * DK + d)) * SS + t0 + t) = dw;
        }
    } else {                                // --- R transpose ---
        int u = bid - 2560;
        int c0 = u * 64;
        #pragma unroll
        for (int p = 0; p < 4; ++p) {
            int dd = (tid >> 4) + p * 16;
            int cc0 = (tid & 15) * 4;
            float4 v = *(const float4*)(R + (size_t)dd * SS + c0 + cc0);
            tl[dd][cc0 + 0] = v.x; tl[dd][cc0 + 1] = v.y;
            tl[dd][cc0 + 2] = v.z; tl[dd][cc0 + 3] = v.w;
        }
        __syncthreads();
        int cc = tid >> 2, q = tid & 3;
        #pragma unroll
        for (int v2 = 0; v2 < 8; ++v2) {
            int d = q * 16 + 2 * v2;
            unsigned dw = ((unsigned)f2bf(tl[d + 1][cc]) << 16) | f2bf(tl[d][cc]);
            *(unsigned*)(RTb + ((size_t)(c0 + cc)) * DK + d) = dw;
        }
    }
}

// ============================================================================
// MFMA flash attention with skewed relative-position bias — KEY-PARITY SPLIT.
// EXACT r11 green kernel (93us kernel, absmax 0.0156, best artifact) with ONE
// change: T5 s_setprio(1)/(0) wrapped around the three MFMA clusters (qpfrag,
// qk, PV). Scheduling-only hint — bit-identical math. r11's 2-blocks/CU x
// 4-wave group structure provides the phase diversity T5 needs (m218b);
// measured +4-7% on attention (m191).
// ============================================================================
__launch_bounds__(256, 1)
__global__ void attn_mfma(const float* __restrict__ Q,
                          const u16* __restrict__ Kb,
                          const u16* __restrict__ VTb,
                          const u16* __restrict__ RTb,
                          float* __restrict__ O) {
    // LDS: 2*16K (per-group V^T) + 16K (QP rings) = 48 KiB
    __shared__ alignas(16) u16 VTl[2][64 * 128];    // [grp][d][t], swz (d&7)<<4
    __shared__ alignas(16) u16 QPl[4][32 * 64];     // per wave ring [q=32][crel&63]

    const int tid  = threadIdx.x;
    const int b    = blockIdx.y;
    const int x    = blockIdx.x;                     // 0..31
    const int jjb  = ((x >> 1) + (b & 7) * 2) & 15;  // per-batch rotation (L2 spread)
    const int flip = (x & 1) ^ ((b >> 3) & 1);
    const int jj   = flip ? (31 - jjb) : jjb;        // 0..31, bijective per batch
    const int S0   = jj * 64;                        // q-tile first row
    const int wave = tid >> 6, lane = tid & 63;
    const int h    = lane >> 5, sl = lane & 31;
    const int grp  = wave >> 1, wv = wave & 1;
    const int s0w  = S0 + wv * 32;                   // wave's first q-row
    const int rtb  = wv ? 0 : 32;                    // wave offset in R window
    const int nTt  = (jj >> 1) + 1;                  // total 128-key tiles
    const int itMax = (nTt + 1) >> 1;                // group-0 count (>= group 1)
    unsigned* QPwU = (unsigned*)&QPl[wave][0];       // ALL QP access via unsigned

    // ---- Q B-fragments (scaled by 1/sqrt(dk)), shared by QK^T and QP ----
    s16x8 bq[4];
    {
        const float* Qr = Q + (size_t)(b * SS + s0w + sl) * DK;
        #pragma unroll
        for (int k = 0; k < 4; ++k) {
            float4 a = *(const float4*)(Qr + 16 * k + 8 * h);
            float4 c = *(const float4*)(Qr + 16 * k + 8 * h + 4);
            u16x8 t;
            t[0] = f2bf(a.x * 0.125f); t[1] = f2bf(a.y * 0.125f);
            t[2] = f2bf(a.z * 0.125f); t[3] = f2bf(a.w * 0.125f);
            t[4] = f2bf(c.x * 0.125f); t[5] = f2bf(c.y * 0.125f);
            t[6] = f2bf(c.z * 0.125f); t[7] = f2bf(c.w * 0.125f);
            bq[k] = __builtin_bit_cast(s16x8, t);
        }
    }

    f32x16 o0 = zero16(), o1 = zero16();
    float m = -3e38f, l = 0.f;

    // QP fragment: window GEMM piece -> rolling LDS ring. A-operand direct
    // from global RTb (element-identical to the old staged reads).
    auto qpfrag = [&](int mi, int cbase) {
        f32x16 acc = zero16();
        int c = cbase + rtb + mi * 32 + sl;
        c = max(0, min(2047, c));                    // clamped rows are masked later
        const u16* Rp = RTb + (size_t)c * DK + 8 * h;
        __builtin_amdgcn_s_setprio(1);
        #pragma unroll
        for (int k = 0; k < 4; ++k) {
            s16x8 a = *(const s16x8*)(Rp + 16 * k);
            acc = __builtin_amdgcn_mfma_f32_32x32x16_bf16(a, bq[k], acc, 0, 0, 0);
        }
        __builtin_amdgcn_s_setprio(0);
        #pragma unroll
        for (int R = 0; R < 4; ++R)
            #pragma unroll
            for (int rp = 0; rp < 2; ++rp) {
                int crel = mi * 32 + 8 * R + 2 * rp + 4 * h;
                unsigned dw = cvtpk(acc[4 * R + 2 * rp], acc[4 * R + 2 * rp + 1]);
                int col = (crel + 2 * sl) & 63;      // bank de-conflict swizzle
                QPwU[sl * 32 + (col >> 1)] = dw;
            }
    };
    auto biasmask = [&](f32x16& s, int ti, int t0, bool fullv) {
        #pragma unroll
        for (int r = 0; r < 16; ++r) {
            int off = (r & 3) + 8 * (r >> 2);
            int col = (31 + ti * 32 + off + 4 * h + sl) & 63;  // (crel + 2*sl)&63
            unsigned dv = QPwU[sl * 32 + (col >> 1)];
            float bias = bf2f((u16)(dv >> ((col & 1) * 16)));
            float v = s[r] + bias;
            if (!fullv) {
                int t = t0 + ti * 32 + off + 4 * h;
                v = (t <= s0w + sl) ? v : -3e38f;
            }
            s[r] = v;
        }
    };

    for (int it = 0; it < itMax; ++it) {
        const int tl = 2 * it + grp;                 // this group's tile
        const bool active = (tl < nTt);
        const int t0 = tl * 128;

        // ---- stage this group's V^T tile (128 threads, 8 chunks each) ----
        if (active) {
            int gtid = tid & 127;
            #pragma unroll
            for (int i = 0; i < 8; ++i) {
                int ch = gtid + i * 128;
                int d = ch >> 4, co = ch & 15;
                u16x8 v = *(const u16x8*)(VTb + (size_t)(b * DK + d) * SS + t0 + co * 8);
                *(u16x8*)((char*)&VTl[grp][0] + d * 256 + ((co * 16) ^ ((d & 7) << 4))) = v;
            }
        }
        __syncthreads();

        if (active) {
            const int cbase = 1984 + t0 - S0;        // R window base (>= 0)
            // ---- K A-fragments direct from global/L2 ----
            s16x8 kf[4][4];
            {
                const u16* Kp = Kb + (size_t)(b * SS + t0 + sl) * DK + 8 * h;
                #pragma unroll
                for (int ti = 0; ti < 4; ++ti)
                    #pragma unroll
                    for (int k = 0; k < 4; ++k)
                        kf[ti][k] = *(const s16x8*)(Kp + ti * 32 * DK + 16 * k);
            }
            auto qk = [&](int ti) -> f32x16 {
                f32x16 acc = zero16();
                __builtin_amdgcn_s_setprio(1);
                #pragma unroll
                for (int k = 0; k < 4; ++k)
                    acc = __builtin_amdgcn_mfma_f32_32x32x16_bf16(kf[ti][k], bq[k], acc, 0, 0, 0);
                __builtin_amdgcn_s_setprio(0);
                return acc;
            };

            const bool fullv = (t0 + 127 <= s0w);
            qpfrag(0, cbase); qpfrag(1, cbase);
            f32x16 s0v = qk(0); biasmask(s0v, 0, t0, fullv);
            qpfrag(2, cbase);
            f32x16 s1v = qk(1); biasmask(s1v, 1, t0, fullv);
            qpfrag(3, cbase);
            f32x16 s2v = qk(2); biasmask(s2v, 2, t0, fullv);
            qpfrag(4, cbase);
            f32x16 s3v = qk(3); biasmask(s3v, 3, t0, fullv);

            // ---- online softmax (column = q-row sl; in-lane + xor32) ----
            float tmax = -3e38f;
            #pragma unroll
            for (int r = 0; r < 16; ++r) {
                tmax = fmaxf(tmax, s0v[r]); tmax = fmaxf(tmax, s1v[r]);
                tmax = fmaxf(tmax, s2v[r]); tmax = fmaxf(tmax, s3v[r]);
            }
            tmax = fmaxf(tmax, __shfl_xor(tmax, 32));
            float mn = fmaxf(m, tmax);
            float corr = __expf(m - mn);
            m = mn;
            float ps = 0.f;
            #pragma unroll
            for (int r = 0; r < 16; ++r) {
                s0v[r] = __expf(s0v[r] - mn); ps += s0v[r];
                s1v[r] = __expf(s1v[r] - mn); ps += s1v[r];
                s2v[r] = __expf(s2v[r] - mn); ps += s2v[r];
                s3v[r] = __expf(s3v[r] - mn); ps += s3v[r];
            }
            l = l * corr + ps;
            #pragma unroll
            for (int r = 0; r < 16; ++r) { o0[r] *= corr; o1[r] *= corr; }

            // ---- pack P to bf16 dword pairs ----
            unsigned pd[4][4][2];
            #define PACK_P(TI, SV)                                            \
                _Pragma("unroll")                                             \
                for (int R = 0; R < 4; ++R) {                                 \
                    pd[TI][R][0] = cvtpk(SV[4 * R + 0], SV[4 * R + 1]);       \
                    pd[TI][R][1] = cvtpk(SV[4 * R + 2], SV[4 * R + 3]);       \
                }
            PACK_P(0, s0v) PACK_P(1, s1v) PACK_P(2, s2v) PACK_P(3, s3v)
            #undef PACK_P

            // ---- PV: O^T += VT . P^T ; B-frags via shfl_xor(32) ----
            #pragma unroll
            for (int c = 0; c < 8; ++c) {
                const int ti = c >> 1;
                const int R0 = (2 * c) & 3, R1 = (2 * c + 1) & 3;
                unsigned a0 = pd[ti][R0][0], a1 = pd[ti][R0][1];
                unsigned b0 = pd[ti][R1][0], b1 = pd[ti][R1][1];
                unsigned xa0 = __shfl_xor(a0, 32), xa1 = __shfl_xor(a1, 32);
                unsigned xb0 = __shfl_xor(b0, 32), xb1 = __shfl_xor(b1, 32);
                u32x4 pw;
                pw[0] = h ? xb0 : a0;
                pw[1] = h ? xb1 : a1;
                pw[2] = h ? b0 : xa0;
                pw[3] = h ? b1 : xa1;
                s16x8 pb = __builtin_bit_cast(s16x8, pw);
                s16x8 va0 = *(const s16x8*)((const char*)&VTl[grp][0] + (0 * 32 + sl) * 256 +
                                            ((32 * c + 16 * h) ^ ((sl & 7) << 4)));
                s16x8 va1 = *(const s16x8*)((const char*)&VTl[grp][0] + (1 * 32 + sl) * 256 +
                                            ((32 * c + 16 * h) ^ ((sl & 7) << 4)));
                __builtin_amdgcn_s_setprio(1);
                o0 = __builtin_amdgcn_mfma_f32_32x32x16_bf16(va0, pb, o0, 0, 0, 0);
                o1 = __builtin_amdgcn_mfma_f32_32x32x16_bf16(va1, pb, o1, 0, 0, 0);
                __builtin_amdgcn_s_setprio(0);
            }
        }
        __syncthreads();
    }

    // ---- merge the two groups' partial flash states (same q-rows) ----
    float* scr = (float*)&VTl[0][0];                 // 2*64*34*4 = 17408B scratch
    if (grp == 1) {
        int base = (wv * 64 + lane) * 34;
        scr[base + 0] = m;
        scr[base + 1] = l;
        #pragma unroll
        for (int j = 0; j < 16; ++j) { scr[base + 2 + j] = o0[j]; scr[base + 18 + j] = o1[j]; }
    }
    __syncthreads();
    if (grp == 0) {
        int base = (wv * 64 + lane) * 34;
        float mB = scr[base + 0], lB = scr[base + 1];
        float M  = fmaxf(m, mB);
        float fa = __expf(m - M), fb = __expf(mB - M);   // inactive group: exp(-inf)=0
        float lt = l * fa + lB * fb;
        #pragma unroll
        for (int j = 0; j < 16; ++j) {
            o0[j] = o0[j] * fa + scr[base + 2 + j] * fb;
            o1[j] = o1[j] * fa + scr[base + 18 + j] * fb;
        }
        lt = lt + __shfl_xor(lt, 32);
        float inv = 1.0f / lt;
        float* Or = O + (size_t)(b * SS + s0w + sl) * DK;
        #pragma unroll
        for (int R = 0; R < 4; ++R) {
            float4 w;
            w.x = o0[4 * R + 0] * inv; w.y = o0[4 * R + 1] * inv;
            w.z = o0[4 * R + 2] * inv; w.w = o0[4 * R + 3] * inv;
            *(float4*)(Or + 8 * R + 4 * h) = w;
            w.x = o1[4 * R + 0] * inv; w.y = o1[4 * R + 1] * inv;
            w.z = o1[4 * R + 2] * inv; w.w = o1[4 * R + 3] * inv;
            *(float4*)(Or + 32 + 8 * R + 4 * h) = w;
        }
    }
}

// ============================================================================
// Fallback (round-1 fp32 kernel) — used only if ws_size is too small.
// ============================================================================
#define RT_ 64
#define TT_ 64
#define NWAVES_ 4
#define PATCH_C_ 128
#define PATCH_STRIDE_ 72

struct MrgT {
    float macc[RT_][DK + 1];
    float mw[NWAVES_][RT_];
    float lw[NWAVES_][RT_];
    float linv[RT_];
};
union SMemT {
    u16 patch[NWAVES_][PATCH_C_ * PATCH_STRIDE_];
    MrgT mrg;
};

__launch_bounds__(256)
__global__ void attn_relpos_fallback(const float* __restrict__ Q,
                                     const float* __restrict__ K,
                                     const float* __restrict__ V,
                                     const float* __restrict__ R,
                                     float* __restrict__ O) {
    __shared__ __attribute__((aligned(16))) SMemT sm;
    const int tileIdx = blockIdx.x;
    const int b       = blockIdx.y;
    const int r0      = tileIdx * RT_;
    const int wave    = __builtin_amdgcn_readfirstlane((int)(threadIdx.x >> 6));
    const int lane    = (int)(threadIdx.x & 63);
    const int s       = r0 + lane;

    float q[DK];
    {
        const float4* Qp = reinterpret_cast<const float4*>(Q + (size_t)(b * SS + s) * DK);
        #pragma unroll
        for (int i = 0; i < DK / 4; ++i) {
            float4 v = Qp[i];
            q[4*i+0] = v.x; q[4*i+1] = v.y; q[4*i+2] = v.z; q[4*i+3] = v.w;
        }
    }
    float acc[DK];
    #pragma unroll
    for (int d = 0; d < DK; ++d) acc[d] = 0.f;
    float m = -1e30f, l = 0.f;
    const int numT = r0 / TT_ + 1;

    for (int ti = wave; ti < numT; ti += NWAVES_) {
        const int t0 = ti * TT_;
        const int c0 = (SS - RT_) + t0 - r0;
        #pragma unroll
        for (int i = 0; i < 32; ++i) {
            const int d  = (lane >> 5) + 2 * i;
            const int cb = (lane & 31) * 4;
            const int c  = c0 + cb;
            float4 v = make_float4(0.f, 0.f, 0.f, 0.f);
            if (c < SS) v = *reinterpret_cast<const float4*>(R + (size_t)d * SS + c);
            u16* pw = &sm.patch[wave][0];
            pw[(cb + 0) * PATCH_STRIDE_ + d] = f2bf(v.x);
            pw[(cb + 1) * PATCH_STRIDE_ + d] = f2bf(v.y);
            pw[(cb + 2) * PATCH_STRIDE_ + d] = f2bf(v.z);
            pw[(cb + 3) * PATCH_STRIDE_ + d] = f2bf(v.w);
        }
        asm volatile("s_waitcnt lgkmcnt(0)" ::: "memory");
        const int ttlim = min(TT_ - 1, (r0 - t0) + lane);
        for (int tc = 0; tc < TT_; tc += 16) {
            float sc[16];
            #pragma unroll
            for (int j = 0; j < 16; ++j) {
                const int tt = tc + j;
                const int t  = t0 + tt;
                const float4* Kt4 = reinterpret_cast<const float4*>(K + (size_t)(b * SS + t) * DK);
                float a0 = 0.f, a1 = 0.f, a2 = 0.f, a3 = 0.f;
                #pragma unroll
                for (int i = 0; i < 16; ++i) {
                    float4 kv = Kt4[i];
                    a0 = fmaf(q[4*i+0], kv.x, a0);
                    a1 = fmaf(q[4*i+1], kv.y, a1);
                    a2 = fmaf(q[4*i+2], kv.z, a2);
                    a3 = fmaf(q[4*i+3], kv.w, a3);
                }
                const int cc = (RT_ - 1) + tt - lane;
                const u16* rp = &sm.patch[wave][cc * PATCH_STRIDE_];
                #pragma unroll
                for (int i = 0; i < 8; ++i) {
                    u16x8 v8 = *reinterpret_cast<const u16x8*>(rp + 8 * i);
                    a0 = fmaf(q[8*i+0], bf2f(v8[0]), a0);
                    a1 = fmaf(q[8*i+1], bf2f(v8[1]), a1);
                    a2 = fmaf(q[8*i+2], bf2f(v8[2]), a2);
                    a3 = fmaf(q[8*i+3], bf2f(v8[3]), a3);
                    a0 = fmaf(q[8*i+4], bf2f(v8[4]), a0);
                    a1 = fmaf(q[8*i+5], bf2f(v8[5]), a1);
                    a2 = fmaf(q[8*i+6], bf2f(v8[6]), a2);
                    a3 = fmaf(q[8*i+7], bf2f(v8[7]), a3);
                }
                const float v = ((a0 + a1) + (a2 + a3)) * 0.125f;
                sc[j] = (tt <= ttlim) ? v : -1e30f;
            }
            float cm = sc[0];
            #pragma unroll
            for (int j = 1; j < 16; ++j) cm = fmaxf(cm, sc[j]);
            const float nm   = fmaxf(m, cm);
            const float corr = __expf(m - nm);
            m = nm; l *= corr;
            #pragma unroll
            for (int d = 0; d < DK; ++d) acc[d] *= corr;
            #pragma unroll
            for (int j = 0; j < 16; ++j) {
                const int t = t0 + tc + j;
                const float p = __expf(sc[j] - m);
                l += p;
                const float4* Vt4 = reinterpret_cast<const float4*>(V + (size_t)(b * SS + t) * DK);
                #pragma unroll
                for (int i = 0; i < 16; ++i) {
                    float4 vv = Vt4[i];
                    acc[4*i+0] = fmaf(p, vv.x, acc[4*i+0]);
                    acc[4*i+1] = fmaf(p, vv.y, acc[4*i+1]);
                    acc[4*i+2] = fmaf(p, vv.z, acc[4*i+2]);
                    acc[4*i+3] = fmaf(p, vv.w, acc[4*i+3]);
                }
            }
        }
    }
    __syncthreads();
    sm.mrg.mw[wave][lane] = m;
    sm.mrg.lw[wave][lane] = l;
    __syncthreads();
    float M = sm.mrg.mw[0][lane];
    #pragma unroll
    for (int w = 1; w < NWAVES_; ++w) M = fmaxf(M, sm.mrg.mw[w][lane]);
    float L = 0.f;
    #pragma unroll
    for (int w = 0; w < NWAVES_; ++w) L += sm.mrg.lw[w][lane] * __expf(sm.mrg.mw[w][lane] - M);
    const float myscale = __expf(m - M);
    for (int w = 0; w < NWAVES_; ++w) {
        if (wave == w) {
            if (w == 0) {
                #pragma unroll
                for (int d = 0; d < DK; ++d) sm.mrg.macc[lane][d] = acc[d] * myscale;
            } else {
                #pragma unroll
                for (int d = 0; d < DK; ++d) sm.mrg.macc[lane][d] += acc[d] * myscale;
            }
        }
        __syncthreads();
    }
    if (wave == 0) sm.mrg.linv[lane] = 1.0f / L;
    __syncthreads();
    const int row = (int)(threadIdx.x >> 2);
    const int dq  = (int)(threadIdx.x & 3) * 16;
    const float li = sm.mrg.linv[row];
    float4* Orow = reinterpret_cast<float4*>(O + (size_t)(b * SS + r0 + row) * DK + dq);
    #pragma unroll
    for (int k2 = 0; k2 < 4; ++k2) {
        float4 o;
        o.x = sm.mrg.macc[row][dq + 4*k2 + 0] * li;
        o.y = sm.mrg.macc[row][dq + 4*k2 + 1] * li;
        o.z = sm.mrg.macc[row][dq + 4*k2 + 2] * li;
        o.w = sm.mrg.macc[row][dq + 4*k2 + 3] * li;
        Orow[k2] = o;
    }
}

extern "C" void kernel_launch(void* const* d_in, const int* in_sizes, int n_in,
                              void* d_out, int out_size, void* d_ws, size_t ws_size,
                              hipStream_t stream) {
    (void)in_sizes; (void)n_in; (void)out_size;
    const float* Q = (const float*)d_in[0];
    const float* K = (const float*)d_in[1];
    const float* V = (const float*)d_in[2];
    const float* R = (const float*)d_in[3];
    float* O = (float*)d_out;

    const size_t KB_ELEMS = (size_t)NB * SS * DK;    // 2,097,152
    const size_t RT_ELEMS = (size_t)SS * DK;         //   131,072
    const size_t NEED = (2 * KB_ELEMS + RT_ELEMS) * sizeof(u16);   // 8,650,752 B

    if (ws_size >= NEED) {
        u16* Kb  = (u16*)d_ws;
        u16* VTb = Kb + KB_ELEMS;
        u16* RTb = VTb + KB_ELEMS;
        prep_kernel<<<2592, 256, 0, stream>>>(K, V, R, Kb, VTb, RTb);
        attn_mfma<<<dim3(32, 16), 256, 0, stream>>>(Q, Kb, VTb, RTb, O);
    } else {
        attn_relpos_fallback<<<dim3(SS / RT_, NB), 256, 0, stream>>>(Q, K, V, R, O);
    }
}

// Round 17
// 98.693 us; speedup vs baseline: 1.4781x; 1.2277x over previous
//
#include <hip/hip_runtime.h>
#include <hip/hip_bf16.h>

#define SS 2048      // sequence per batch after reshape
#define DK 64        // head dim
#define NB 16        // batches after reshape

typedef unsigned short u16;
typedef u16   u16x8 __attribute__((ext_vector_type(8)));
typedef u16   u16x4 __attribute__((ext_vector_type(4)));
typedef short s16x8 __attribute__((ext_vector_type(8)));
typedef float f32x16 __attribute__((ext_vector_type(16)));
typedef unsigned u32x4 __attribute__((ext_vector_type(4)));

__device__ __forceinline__ u16 f2bf(float f) {
    unsigned u = __builtin_bit_cast(unsigned, f);
    return (u16)((u + 0x7fffu + ((u >> 16) & 1u)) >> 16);   // RNE
}
__device__ __forceinline__ float bf2f(u16 v) {
    unsigned u = ((unsigned)v) << 16;
    return __builtin_bit_cast(float, u);
}
__device__ __forceinline__ unsigned cvtpk(float lo, float hi) {
    unsigned d;
    asm("v_cvt_pk_bf16_f32 %0, %1, %2" : "=v"(d) : "v"(lo), "v"(hi));
    return d;
}
__device__ __forceinline__ f32x16 zero16() {
    f32x16 z;
    #pragma unroll
    for (int i = 0; i < 16; ++i) z[i] = 0.f;
    return z;
}

// ============================================================================
// Prep: K -> bf16 Kb[b][t][d]; V -> bf16 VTb[b][d][t]; R -> bf16 RTb[c][d]
// One kernel, block-ranges: [0,2048)=K, [2048,2560)=V^T, [2560,2592)=R^T
// ============================================================================
__launch_bounds__(256)
__global__ void prep_kernel(const float* __restrict__ K,
                            const float* __restrict__ V,
                            const float* __restrict__ R,
                            u16* __restrict__ Kb,
                            u16* __restrict__ VTb,
                            u16* __restrict__ RTb) {
    __shared__ float tl[64][65];
    const int bid = blockIdx.x, tid = threadIdx.x;

    if (bid < 2048) {                       // --- K elementwise convert ---
        size_t i0 = ((size_t)bid * 256 + tid) * 4;
        float4 v = *(const float4*)(K + i0);
        u16x4 o;
        o[0] = f2bf(v.x); o[1] = f2bf(v.y); o[2] = f2bf(v.z); o[3] = f2bf(v.w);
        *(u16x4*)(Kb + i0) = o;
    } else if (bid < 2560) {                // --- V transpose (per batch) ---
        int u = bid - 2048;
        int bb = u >> 5, t0 = (u & 31) * 64;
        #pragma unroll
        for (int p = 0; p < 4; ++p) {
            int tt = (tid >> 4) + p * 16;
            int d0 = (tid & 15) * 4;
            float4 v = *(const float4*)(V + ((size_t)(bb * SS + t0 + tt)) * DK + d0);
            tl[tt][d0 + 0] = v.x; tl[tt][d0 + 1] = v.y;
            tl[tt][d0 + 2] = v.z; tl[tt][d0 + 3] = v.w;
        }
        __syncthreads();
        int d = tid >> 2, q = tid & 3;
        #pragma unroll
        for (int v2 = 0; v2 < 8; ++v2) {
            int t = q * 16 + 2 * v2;
            unsigned dw = ((unsigned)f2bf(tl[t + 1][d]) << 16) | f2bf(tl[t][d]);
            *(unsigned*)(VTb + ((size_t)(bb * DK + d)) * SS + t0 + t) = dw;
        }
    } else {                                // --- R transpose ---
        int u = bid - 2560;
        int c0 = u * 64;
        #pragma unroll
        for (int p = 0; p < 4; ++p) {
            int dd = (tid >> 4) + p * 16;
            int cc0 = (tid & 15) * 4;
            float4 v = *(const float4*)(R + (size_t)dd * SS + c0 + cc0);
            tl[dd][cc0 + 0] = v.x; tl[dd][cc0 + 1] = v.y;
            tl[dd][cc0 + 2] = v.z; tl[dd][cc0 + 3] = v.w;
        }
        __syncthreads();
        int cc = tid >> 2, q = tid & 3;
        #pragma unroll
        for (int v2 = 0; v2 < 8; ++v2) {
            int d = q * 16 + 2 * v2;
            unsigned dw = ((unsigned)f2bf(tl[d + 1][cc]) << 16) | f2bf(tl[d][cc]);
            *(unsigned*)(RTb + ((size_t)(c0 + cc)) * DK + d) = dw;
        }
    }
}

// ============================================================================
// MFMA flash attention with skewed relative-position bias — KEY-PARITY SPLIT,
// DOUBLE-BUFFERED V. r11 green engine (93us kernel, best artifact; setprio
// reverted — r16 showed it regresses) with ONE structural change: per-group
// V^T tiles are double-buffered. Iteration it: stage tile (it+1)'s V into
// buf^1 (overlaps compute), compute from buf, ONE barrier at iteration end
// (r11 had 2). Ordering: ring write->read intra-wave within one inter-barrier
// region (same as r11); VTl read-buf and write-buf disjoint; every cross-
// iteration reuse crosses >=1 barrier (the r13 zero-barrier hazard avoided).
// LDS 80KB -> exactly 2 blocks/CU. Engine/map/merge byte-identical to r11.
// ============================================================================
__launch_bounds__(256, 1)
__global__ void attn_mfma(const float* __restrict__ Q,
                          const u16* __restrict__ Kb,
                          const u16* __restrict__ VTb,
                          const u16* __restrict__ RTb,
                          float* __restrict__ O) {
    // LDS: 2 grp x 2 buf x 16K (V^T) + 16K (QP rings) = 80 KiB
    __shared__ alignas(16) u16 VTl[2][2][64 * 128]; // [grp][buf][d][t], swz (d&7)<<4
    __shared__ alignas(16) u16 QPl[4][32 * 64];     // per wave ring [q=32][crel&63]

    const int tid  = threadIdx.x;
    const int b    = blockIdx.y;
    const int x    = blockIdx.x;                     // 0..31
    const int jjb  = ((x >> 1) + (b & 7) * 2) & 15;  // per-batch rotation (L2 spread)
    const int flip = (x & 1) ^ ((b >> 3) & 1);
    const int jj   = flip ? (31 - jjb) : jjb;        // 0..31, bijective per batch
    const int S0   = jj * 64;                        // q-tile first row
    const int wave = tid >> 6, lane = tid & 63;
    const int h    = lane >> 5, sl = lane & 31;
    const int grp  = wave >> 1, wv = wave & 1;
    const int s0w  = S0 + wv * 32;                   // wave's first q-row
    const int rtb  = wv ? 0 : 32;                    // wave offset in R window
    const int nTt  = (jj >> 1) + 1;                  // total 128-key tiles
    const int itMax = (nTt + 1) >> 1;                // group-0 count (>= group 1)
    unsigned* QPwU = (unsigned*)&QPl[wave][0];       // ALL QP access via unsigned

    // ---- Q B-fragments (scaled by 1/sqrt(dk)), shared by QK^T and QP ----
    s16x8 bq[4];
    {
        const float* Qr = Q + (size_t)(b * SS + s0w + sl) * DK;
        #pragma unroll
        for (int k = 0; k < 4; ++k) {
            float4 a = *(const float4*)(Qr + 16 * k + 8 * h);
            float4 c = *(const float4*)(Qr + 16 * k + 8 * h + 4);
            u16x8 t;
            t[0] = f2bf(a.x * 0.125f); t[1] = f2bf(a.y * 0.125f);
            t[2] = f2bf(a.z * 0.125f); t[3] = f2bf(a.w * 0.125f);
            t[4] = f2bf(c.x * 0.125f); t[5] = f2bf(c.y * 0.125f);
            t[6] = f2bf(c.z * 0.125f); t[7] = f2bf(c.w * 0.125f);
            bq[k] = __builtin_bit_cast(s16x8, t);
        }
    }

    f32x16 o0 = zero16(), o1 = zero16();
    float m = -3e38f, l = 0.f;

    // Stage one 128-key V^T tile for this group into buffer bufidx.
    auto stageV = [&](int tl, int bufidx) {
        const int t0s = tl * 128;
        int gtid = tid & 127;
        #pragma unroll
        for (int i = 0; i < 8; ++i) {
            int ch = gtid + i * 128;
            int d = ch >> 4, co = ch & 15;
            u16x8 v = *(const u16x8*)(VTb + (size_t)(b * DK + d) * SS + t0s + co * 8);
            *(u16x8*)((char*)&VTl[grp][bufidx][0] + d * 256 + ((co * 16) ^ ((d & 7) << 4))) = v;
        }
    };

    // QP fragment: window GEMM piece -> rolling LDS ring. A-operand direct
    // from global RTb (element-identical to the old staged reads).
    auto qpfrag = [&](int mi, int cbase) {
        f32x16 acc = zero16();
        int c = cbase + rtb + mi * 32 + sl;
        c = max(0, min(2047, c));                    // clamped rows are masked later
        const u16* Rp = RTb + (size_t)c * DK + 8 * h;
        #pragma unroll
        for (int k = 0; k < 4; ++k) {
            s16x8 a = *(const s16x8*)(Rp + 16 * k);
            acc = __builtin_amdgcn_mfma_f32_32x32x16_bf16(a, bq[k], acc, 0, 0, 0);
        }
        #pragma unroll
        for (int R = 0; R < 4; ++R)
            #pragma unroll
            for (int rp = 0; rp < 2; ++rp) {
                int crel = mi * 32 + 8 * R + 2 * rp + 4 * h;
                unsigned dw = cvtpk(acc[4 * R + 2 * rp], acc[4 * R + 2 * rp + 1]);
                int col = (crel + 2 * sl) & 63;      // bank de-conflict swizzle
                QPwU[sl * 32 + (col >> 1)] = dw;
            }
    };
    auto biasmask = [&](f32x16& s, int ti, int t0, bool fullv) {
        #pragma unroll
        for (int r = 0; r < 16; ++r) {
            int off = (r & 3) + 8 * (r >> 2);
            int col = (31 + ti * 32 + off + 4 * h + sl) & 63;  // (crel + 2*sl)&63
            unsigned dv = QPwU[sl * 32 + (col >> 1)];
            float bias = bf2f((u16)(dv >> ((col & 1) * 16)));
            float v = s[r] + bias;
            if (!fullv) {
                int t = t0 + ti * 32 + off + 4 * h;
                v = (t <= s0w + sl) ? v : -3e38f;
            }
            s[r] = v;
        }
    };

    // ---- prologue: stage each group's first tile into buffer 0 ----
    if (grp < nTt) stageV(grp, 0);
    __syncthreads();

    for (int it = 0; it < itMax; ++it) {
        const int tl = 2 * it + grp;                 // this group's tile
        const bool active = (tl < nTt);
        const int t0 = tl * 128;
        const int buf = it & 1;

        // ---- stage NEXT tile into the other buffer (overlaps compute) ----
        {
            const int tln = 2 * (it + 1) + grp;
            if (tln < nTt) stageV(tln, buf ^ 1);
        }

        if (active) {
            const int cbase = 1984 + t0 - S0;        // R window base (>= 0)
            // ---- K A-fragments direct from global/L2 ----
            s16x8 kf[4][4];
            {
                const u16* Kp = Kb + (size_t)(b * SS + t0 + sl) * DK + 8 * h;
                #pragma unroll
                for (int ti = 0; ti < 4; ++ti)
                    #pragma unroll
                    for (int k = 0; k < 4; ++k)
                        kf[ti][k] = *(const s16x8*)(Kp + ti * 32 * DK + 16 * k);
            }
            auto qk = [&](int ti) -> f32x16 {
                f32x16 acc = zero16();
                #pragma unroll
                for (int k = 0; k < 4; ++k)
                    acc = __builtin_amdgcn_mfma_f32_32x32x16_bf16(kf[ti][k], bq[k], acc, 0, 0, 0);
                return acc;
            };

            const bool fullv = (t0 + 127 <= s0w);
            qpfrag(0, cbase); qpfrag(1, cbase);
            f32x16 s0v = qk(0); biasmask(s0v, 0, t0, fullv);
            qpfrag(2, cbase);
            f32x16 s1v = qk(1); biasmask(s1v, 1, t0, fullv);
            qpfrag(3, cbase);
            f32x16 s2v = qk(2); biasmask(s2v, 2, t0, fullv);
            qpfrag(4, cbase);
            f32x16 s3v = qk(3); biasmask(s3v, 3, t0, fullv);

            // ---- online softmax (column = q-row sl; in-lane + xor32) ----
            float tmax = -3e38f;
            #pragma unroll
            for (int r = 0; r < 16; ++r) {
                tmax = fmaxf(tmax, s0v[r]); tmax = fmaxf(tmax, s1v[r]);
                tmax = fmaxf(tmax, s2v[r]); tmax = fmaxf(tmax, s3v[r]);
            }
            tmax = fmaxf(tmax, __shfl_xor(tmax, 32));
            float mn = fmaxf(m, tmax);
            float corr = __expf(m - mn);
            m = mn;
            float ps = 0.f;
            #pragma unroll
            for (int r = 0; r < 16; ++r) {
                s0v[r] = __expf(s0v[r] - mn); ps += s0v[r];
                s1v[r] = __expf(s1v[r] - mn); ps += s1v[r];
                s2v[r] = __expf(s2v[r] - mn); ps += s2v[r];
                s3v[r] = __expf(s3v[r] - mn); ps += s3v[r];
            }
            l = l * corr + ps;
            #pragma unroll
            for (int r = 0; r < 16; ++r) { o0[r] *= corr; o1[r] *= corr; }

            // ---- pack P to bf16 dword pairs ----
            unsigned pd[4][4][2];
            #define PACK_P(TI, SV)                                            \
                _Pragma("unroll")                                             \
                for (int R = 0; R < 4; ++R) {                                 \
                    pd[TI][R][0] = cvtpk(SV[4 * R + 0], SV[4 * R + 1]);       \
                    pd[TI][R][1] = cvtpk(SV[4 * R + 2], SV[4 * R + 3]);       \
                }
            PACK_P(0, s0v) PACK_P(1, s1v) PACK_P(2, s2v) PACK_P(3, s3v)
            #undef PACK_P

            // ---- PV: O^T += VT . P^T ; B-frags via shfl_xor(32) ----
            #pragma unroll
            for (int c = 0; c < 8; ++c) {
                const int ti = c >> 1;
                const int R0 = (2 * c) & 3, R1 = (2 * c + 1) & 3;
                unsigned a0 = pd[ti][R0][0], a1 = pd[ti][R0][1];
                unsigned b0 = pd[ti][R1][0], b1 = pd[ti][R1][1];
                unsigned xa0 = __shfl_xor(a0, 32), xa1 = __shfl_xor(a1, 32);
                unsigned xb0 = __shfl_xor(b0, 32), xb1 = __shfl_xor(b1, 32);
                u32x4 pw;
                pw[0] = h ? xb0 : a0;
                pw[1] = h ? xb1 : a1;
                pw[2] = h ? b0 : xa0;
                pw[3] = h ? b1 : xa1;
                s16x8 pb = __builtin_bit_cast(s16x8, pw);
                s16x8 va0 = *(const s16x8*)((const char*)&VTl[grp][buf][0] + (0 * 32 + sl) * 256 +
                                            ((32 * c + 16 * h) ^ ((sl & 7) << 4)));
                s16x8 va1 = *(const s16x8*)((const char*)&VTl[grp][buf][0] + (1 * 32 + sl) * 256 +
                                            ((32 * c + 16 * h) ^ ((sl & 7) << 4)));
                o0 = __builtin_amdgcn_mfma_f32_32x32x16_bf16(va0, pb, o0, 0, 0, 0);
                o1 = __builtin_amdgcn_mfma_f32_32x32x16_bf16(va1, pb, o1, 0, 0, 0);
            }
        }
        __syncthreads();   // single per-iteration fence (protects both buffers)
    }

    // ---- merge the two groups' partial flash states (same q-rows) ----
    float* scr = (float*)&VTl[0][0][0];              // 2*64*34*4 = 17408B scratch
    if (grp == 1) {
        int base = (wv * 64 + lane) * 34;
        scr[base + 0] = m;
        scr[base + 1] = l;
        #pragma unroll
        for (int j = 0; j < 16; ++j) { scr[base + 2 + j] = o0[j]; scr[base + 18 + j] = o1[j]; }
    }
    __syncthreads();
    if (grp == 0) {
        int base = (wv * 64 + lane) * 34;
        float mB = scr[base + 0], lB = scr[base + 1];
        float M  = fmaxf(m, mB);
        float fa = __expf(m - M), fb = __expf(mB - M);   // inactive group: exp(-inf)=0
        float lt = l * fa + lB * fb;
        #pragma unroll
        for (int j = 0; j < 16; ++j) {
            o0[j] = o0[j] * fa + scr[base + 2 + j] * fb;
            o1[j] = o1[j] * fa + scr[base + 18 + j] * fb;
        }
        lt = lt + __shfl_xor(lt, 32);
        float inv = 1.0f / lt;
        float* Or = O + (size_t)(b * SS + s0w + sl) * DK;
        #pragma unroll
        for (int R = 0; R < 4; ++R) {
            float4 w;
            w.x = o0[4 * R + 0] * inv; w.y = o0[4 * R + 1] * inv;
            w.z = o0[4 * R + 2] * inv; w.w = o0[4 * R + 3] * inv;
            *(float4*)(Or + 8 * R + 4 * h) = w;
            w.x = o1[4 * R + 0] * inv; w.y = o1[4 * R + 1] * inv;
            w.z = o1[4 * R + 2] * inv; w.w = o1[4 * R + 3] * inv;
            *(float4*)(Or + 32 + 8 * R + 4 * h) = w;
        }
    }
}

// ============================================================================
// Fallback (round-1 fp32 kernel) — used only if ws_size is too small.
// ============================================================================
#define RT_ 64
#define TT_ 64
#define NWAVES_ 4
#define PATCH_C_ 128
#define PATCH_STRIDE_ 72

struct MrgT {
    float macc[RT_][DK + 1];
    float mw[NWAVES_][RT_];
    float lw[NWAVES_][RT_];
    float linv[RT_];
};
union SMemT {
    u16 patch[NWAVES_][PATCH_C_ * PATCH_STRIDE_];
    MrgT mrg;
};

__launch_bounds__(256)
__global__ void attn_relpos_fallback(const float* __restrict__ Q,
                                     const float* __restrict__ K,
                                     const float* __restrict__ V,
                                     const float* __restrict__ R,
                                     float* __restrict__ O) {
    __shared__ __attribute__((aligned(16))) SMemT sm;
    const int tileIdx = blockIdx.x;
    const int b       = blockIdx.y;
    const int r0      = tileIdx * RT_;
    const int wave    = __builtin_amdgcn_readfirstlane((int)(threadIdx.x >> 6));
    const int lane    = (int)(threadIdx.x & 63);
    const int s       = r0 + lane;

    float q[DK];
    {
        const float4* Qp = reinterpret_cast<const float4*>(Q + (size_t)(b * SS + s) * DK);
        #pragma unroll
        for (int i = 0; i < DK / 4; ++i) {
            float4 v = Qp[i];
            q[4*i+0] = v.x; q[4*i+1] = v.y; q[4*i+2] = v.z; q[4*i+3] = v.w;
        }
    }
    float acc[DK];
    #pragma unroll
    for (int d = 0; d < DK; ++d) acc[d] = 0.f;
    float m = -1e30f, l = 0.f;
    const int numT = r0 / TT_ + 1;

    for (int ti = wave; ti < numT; ti += NWAVES_) {
        const int t0 = ti * TT_;
        const int c0 = (SS - RT_) + t0 - r0;
        #pragma unroll
        for (int i = 0; i < 32; ++i) {
            const int d  = (lane >> 5) + 2 * i;
            const int cb = (lane & 31) * 4;
            const int c  = c0 + cb;
            float4 v = make_float4(0.f, 0.f, 0.f, 0.f);
            if (c < SS) v = *reinterpret_cast<const float4*>(R + (size_t)d * SS + c);
            u16* pw = &sm.patch[wave][0];
            pw[(cb + 0) * PATCH_STRIDE_ + d] = f2bf(v.x);
            pw[(cb + 1) * PATCH_STRIDE_ + d] = f2bf(v.y);
            pw[(cb + 2) * PATCH_STRIDE_ + d] = f2bf(v.z);
            pw[(cb + 3) * PATCH_STRIDE_ + d] = f2bf(v.w);
        }
        asm volatile("s_waitcnt lgkmcnt(0)" ::: "memory");
        const int ttlim = min(TT_ - 1, (r0 - t0) + lane);
        for (int tc = 0; tc < TT_; tc += 16) {
            float sc[16];
            #pragma unroll
            for (int j = 0; j < 16; ++j) {
                const int tt = tc + j;
                const int t  = t0 + tt;
                const float4* Kt4 = reinterpret_cast<const float4*>(K + (size_t)(b * SS + t) * DK);
                float a0 = 0.f, a1 = 0.f, a2 = 0.f, a3 = 0.f;
                #pragma unroll
                for (int i = 0; i < 16; ++i) {
                    float4 kv = Kt4[i];
                    a0 = fmaf(q[4*i+0], kv.x, a0);
                    a1 = fmaf(q[4*i+1], kv.y, a1);
                    a2 = fmaf(q[4*i+2], kv.z, a2);
                    a3 = fmaf(q[4*i+3], kv.w, a3);
                }
                const int cc = (RT_ - 1) + tt - lane;
                const u16* rp = &sm.patch[wave][cc * PATCH_STRIDE_];
                #pragma unroll
                for (int i = 0; i < 8; ++i) {
                    u16x8 v8 = *reinterpret_cast<const u16x8*>(rp + 8 * i);
                    a0 = fmaf(q[8*i+0], bf2f(v8[0]), a0);
                    a1 = fmaf(q[8*i+1], bf2f(v8[1]), a1);
                    a2 = fmaf(q[8*i+2], bf2f(v8[2]), a2);
                    a3 = fmaf(q[8*i+3], bf2f(v8[3]), a3);
                    a0 = fmaf(q[8*i+4], bf2f(v8[4]), a0);
                    a1 = fmaf(q[8*i+5], bf2f(v8[5]), a1);
                    a2 = fmaf(q[8*i+6], bf2f(v8[6]), a2);
                    a3 = fmaf(q[8*i+7], bf2f(v8[7]), a3);
                }
                const float v = ((a0 + a1) + (a2 + a3)) * 0.125f;
                sc[j] = (tt <= ttlim) ? v : -1e30f;
            }
            float cm = sc[0];
            #pragma unroll
            for (int j = 1; j < 16; ++j) cm = fmaxf(cm, sc[j]);
            const float nm   = fmaxf(m, cm);
            const float corr = __expf(m - nm);
            m = nm; l *= corr;
            #pragma unroll
            for (int d = 0; d < DK; ++d) acc[d] *= corr;
            #pragma unroll
            for (int j = 0; j < 16; ++j) {
                const int t = t0 + tc + j;
                const float p = __expf(sc[j] - m);
                l += p;
                const float4* Vt4 = reinterpret_cast<const float4*>(V + (size_t)(b * SS + t) * DK);
                #pragma unroll
                for (int i = 0; i < 16; ++i) {
                    float4 vv = Vt4[i];
                    acc[4*i+0] = fmaf(p, vv.x, acc[4*i+0]);
                    acc[4*i+1] = fmaf(p, vv.y, acc[4*i+1]);
                    acc[4*i+2] = fmaf(p, vv.z, acc[4*i+2]);
                    acc[4*i+3] = fmaf(p, vv.w, acc[4*i+3]);
                }
            }
        }
    }
    __syncthreads();
    sm.mrg.mw[wave][lane] = m;
    sm.mrg.lw[wave][lane] = l;
    __syncthreads();
    float M = sm.mrg.mw[0][lane];
    #pragma unroll
    for (int w = 1; w < NWAVES_; ++w) M = fmaxf(M, sm.mrg.mw[w][lane]);
    float L = 0.f;
    #pragma unroll
    for (int w = 0; w < NWAVES_; ++w) L += sm.mrg.lw[w][lane] * __expf(sm.mrg.mw[w][lane] - M);
    const float myscale = __expf(m - M);
    for (int w = 0; w < NWAVES_; ++w) {
        if (wave == w) {
            if (w == 0) {
                #pragma unroll
                for (int d = 0; d < DK; ++d) sm.mrg.macc[lane][d] = acc[d] * myscale;
            } else {
                #pragma unroll
                for (int d = 0; d < DK; ++d) sm.mrg.macc[lane][d] += acc[d] * myscale;
            }
        }
        __syncthreads();
    }
    if (wave == 0) sm.mrg.linv[lane] = 1.0f / L;
    __syncthreads();
    const int row = (int)(threadIdx.x >> 2);
    const int dq  = (int)(threadIdx.x & 3) * 16;
    const float li = sm.mrg.linv[row];
    float4* Orow = reinterpret_cast<float4*>(O + (size_t)(b * SS + r0 + row) * DK + dq);
    #pragma unroll
    for (int k2 = 0; k2 < 4; ++k2) {
        float4 o;
        o.x = sm.mrg.macc[row][dq + 4*k2 + 0] * li;
        o.y = sm.mrg.macc[row][dq + 4*k2 + 1] * li;
        o.z = sm.mrg.macc[row][dq + 4*k2 + 2] * li;
        o.w = sm.mrg.macc[row][dq + 4*k2 + 3] * li;
        Orow[k2] = o;
    }
}

extern "C" void kernel_launch(void* const* d_in, const int* in_sizes, int n_in,
                              void* d_out, int out_size, void* d_ws, size_t ws_size,
                              hipStream_t stream) {
    (void)in_sizes; (void)n_in; (void)out_size;
    const float* Q = (const float*)d_in[0];
    const float* K = (const float*)d_in[1];
    const float* V = (const float*)d_in[2];
    const float* R = (const float*)d_in[3];
    float* O = (float*)d_out;

    const size_t KB_ELEMS = (size_t)NB * SS * DK;    // 2,097,152
    const size_t RT_ELEMS = (size_t)SS * DK;         //   131,072
    const size_t NEED = (2 * KB_ELEMS + RT_ELEMS) * sizeof(u16);   // 8,650,752 B

    if (ws_size >= NEED) {
        u16* Kb  = (u16*)d_ws;
        u16* VTb = Kb + KB_ELEMS;
        u16* RTb = VTb + KB_ELEMS;
        prep_kernel<<<2592, 256, 0, stream>>>(K, V, R, Kb, VTb, RTb);
        attn_mfma<<<dim3(32, 16), 256, 0, stream>>>(Q, Kb, VTb, RTb, O);
    } else {
        attn_relpos_fallback<<<dim3(SS / RT_, NB), 256, 0, stream>>>(Q, K, V, R, O);
    }
}